// Round 6
// baseline (218.872 us; speedup 1.0000x reference)
//
#include <hip/hip_runtime.h>
#include <hip/hip_bf16.h>

#define S_LEN 1024
#define DIN 4096
#define NH 32
#define NG 8
#define HD 128

typedef __bf16 bf16x8 __attribute__((ext_vector_type(8)));
typedef __bf16 bf16x4 __attribute__((ext_vector_type(4)));
typedef float f32x4 __attribute__((ext_vector_type(4)));

__device__ __forceinline__ void gload_lds16(const void* g, void* l) {
  __builtin_amdgcn_global_load_lds(
      (const __attribute__((address_space(1))) unsigned int*)g,
      (__attribute__((address_space(3))) unsigned int*)l, 16, 0, 0);
}

__device__ __forceinline__ unsigned pack2bf(float a, float b) {
  union { __bf16 h[2]; unsigned u; } x;
  x.h[0] = (__bf16)a; x.h[1] = (__bf16)b;
  return x.u;
}

// ---------------- fused prep: cast x + transpose+cast all weights ----------------
// blocks [0,4096): cast x (float4 -> bf16x4)
// blocks [4096,  8192): Wq tiles -> WqkvT rows [0,4096)
// blocks [8192,  9216): Wk tiles -> WqkvT rows [4096,5120)
// blocks [9216, 10240): Wv tiles -> WqkvT rows [5120,6144)
// blocks [10240,14336): Wo tiles -> WoT
// Transpose: k-pair dword packing, derived conflict-free banking.
//   t3 dword tile [32 kp][16 chunk][4]; logical chunk c of row kp stored at
//   physical chunk c ^ (kp & 7) (involution used by both writer and reader).
__global__ __launch_bounds__(256) void k_prep(const float* __restrict__ x,
                                              const float* __restrict__ Wq,
                                              const float* __restrict__ Wk,
                                              const float* __restrict__ Wv,
                                              const float* __restrict__ Wo,
                                              __bf16* __restrict__ xb,
                                              __bf16* __restrict__ WqkvT,
                                              __bf16* __restrict__ WoT) {
  __shared__ unsigned t3[32 * 64];  // 8 KB
  const int tid = threadIdx.x;
  int bid = blockIdx.x;
  if (bid < 4096) {
    int i = bid * 256 + tid;
    const float4 v = ((const float4*)x)[i];
    bf16x4 o;
    o.x = (__bf16)v.x; o.y = (__bf16)v.y; o.z = (__bf16)v.z; o.w = (__bf16)v.w;
    ((bf16x4*)xb)[i] = o;
    return;
  }
  bid -= 4096;
  const float* W; __bf16* WT; int N, off, tau;
  if (bid < 4096)       { W = Wq; WT = WqkvT; N = 4096; off = 0;    tau = bid; }
  else if (bid < 5120)  { W = Wk; WT = WqkvT; N = 1024; off = 4096; tau = bid - 4096; }
  else if (bid < 6144)  { W = Wv; WT = WqkvT; N = 1024; off = 5120; tau = bid - 5120; }
  else                  { W = Wo; WT = WoT;   N = 4096; off = 0;    tau = bid - 6144; }
  const int ntx = N >> 6;
  const int n0 = (tau % ntx) * 64, k0 = (tau / ntx) * 64;

  // ---- Phase W: global (2 coalesced rows) -> packed dwords -> b128 LDS write ----
#pragma unroll
  for (int p = 0; p < 2; ++p) {
    int kp = (tid >> 4) + 16 * p;   // 0..31 (k-pair row)
    int nn = (tid & 15) * 4;        // col group
    const float4 a = *(const float4*)&W[(size_t)(k0 + 2 * kp) * N + n0 + nn];
    const float4 b = *(const float4*)&W[(size_t)(k0 + 2 * kp + 1) * N + n0 + nn];
    int cphys = (nn >> 2) ^ (kp & 7);
    uint4 d;
    d.x = pack2bf(a.x, b.x);
    d.y = pack2bf(a.y, b.y);
    d.z = pack2bf(a.z, b.z);
    d.w = pack2bf(a.w, b.w);
    *(uint4*)&t3[kp * 64 + cphys * 4] = d;
  }
  __syncthreads();

  // ---- Phase R: 4 scalar b32 reads down kp (2-way banks) -> b128 global write ----
#pragma unroll
  for (int s = 0; s < 2; ++s) {
    int n = tid & 63;               // output row (original col)
    int cc = (tid >> 6) + 4 * s;    // k-chunk: covers k = 8cc..8cc+7
    uint4 d;
    {
      int kp0 = 4 * cc;
      d.x = t3[(kp0 + 0) * 64 + (((n >> 2) ^ ((kp0 + 0) & 7)) << 2) + (n & 3)];
      d.y = t3[(kp0 + 1) * 64 + (((n >> 2) ^ ((kp0 + 1) & 7)) << 2) + (n & 3)];
      d.z = t3[(kp0 + 2) * 64 + (((n >> 2) ^ ((kp0 + 2) & 7)) << 2) + (n & 3)];
      d.w = t3[(kp0 + 3) * 64 + (((n >> 2) ^ ((kp0 + 3) & 7)) << 2) + (n & 3)];
    }
    *(uint4*)&WT[(size_t)(off + n0 + n) * DIN + k0 + 8 * cc] = d;
  }
}

// ---------------- RoPE, vectorized: 4 d-pairs per thread ----------------
__global__ __launch_bounds__(256) void k_rope(__bf16* __restrict__ Q, __bf16* __restrict__ Kb,
                                              const float* __restrict__ cosT,
                                              const float* __restrict__ sinT) {
  int idx = blockIdx.x * 256 + threadIdx.x;
  int d = (idx & 15) * 4;
  int row = idx >> 4;
  __bf16* p; int s;
  if (row < S_LEN * NH) { p = Q + (size_t)row * HD; s = row >> 5; }
  else { int r = row - S_LEN * NH; p = Kb + (size_t)r * HD; s = r >> 3; }
  const float4 c = *(const float4*)&cosT[s * HD + d];
  const float4 sn = *(const float4*)&sinT[s * HD + d];
  bf16x4 a = *(const bf16x4*)&p[d];
  bf16x4 b = *(const bf16x4*)&p[d + 64];
  bf16x4 oa, ob;
  oa.x = (__bf16)((float)a.x * c.x - (float)b.x * sn.x);
  oa.y = (__bf16)((float)a.y * c.y - (float)b.y * sn.y);
  oa.z = (__bf16)((float)a.z * c.z - (float)b.z * sn.z);
  oa.w = (__bf16)((float)a.w * c.w - (float)b.w * sn.w);
  ob.x = (__bf16)((float)b.x * c.x + (float)a.x * sn.x);
  ob.y = (__bf16)((float)b.y * c.y + (float)a.y * sn.y);
  ob.z = (__bf16)((float)b.z * c.z + (float)a.z * sn.z);
  ob.w = (__bf16)((float)b.w * c.w + (float)a.w * sn.w);
  *(bf16x4*)&p[d] = oa;
  *(bf16x4*)&p[d + 64] = ob;
}

// ---------------- GEMM: C(M,N) = A(M,K) * Bt(N,K)^T, bf16 in ----------------
// BM=128, BN=64, BK=64. 4 waves. Round-2 proven layout (0 bank conflicts):
// all LDS writes via global_load_lds DMA, 3-bit XOR chunk swizzle, b128 frag reads.
// Double-buffered + prefetch(t+1) issued before compute(t), 1 barrier/iter.
// MODE 0: f32 C (N=4096). MODE 1: QKV split epilogue (Q,K bf16; V written transposed).
template <int MODE>
__global__ __launch_bounds__(256, 3) void k_gemm(const __bf16* __restrict__ A,
                                                 const __bf16* __restrict__ Bt,
                                                 float* __restrict__ C,
                                                 __bf16* __restrict__ Qb,
                                                 __bf16* __restrict__ Kb,
                                                 __bf16* __restrict__ Vt) {
  __shared__ __bf16 As[2][128 * 64];
  __shared__ __bf16 Bs[2][64 * 64];
  const int bm = blockIdx.y, bn = blockIdx.x;
  const int K = DIN, NT = K / 64;

  const int tid = threadIdx.x, w = tid >> 6;
  const int l = tid & 63, l15 = l & 15, g4 = l >> 4;

  const __bf16* Asrc = A + (size_t)(bm * 128) * K;
  const __bf16* Bsrc = Bt + (size_t)(bn * 64) * K;

  f32x4 acc[2][4];
#pragma unroll
  for (int i = 0; i < 2; ++i)
#pragma unroll
    for (int j = 0; j < 4; ++j)
#pragma unroll
      for (int r = 0; r < 4; ++r) acc[i][j][r] = 0.f;

  auto issueA = [&](int t, __bf16* dst) {
#pragma unroll
    for (int p = 0; p < 4; ++p) {
      int c = p * 256 + tid;
      int row = c >> 3, gc = (c & 7) ^ (row & 7);
      gload_lds16(Asrc + (size_t)row * K + t * 64 + gc * 8, dst + (p * 256 + w * 64) * 8);
    }
  };
  auto issueB = [&](int t, __bf16* dst) {
#pragma unroll
    for (int p = 0; p < 2; ++p) {
      int c = p * 256 + tid;
      int row = c >> 3, gc = (c & 7) ^ (row & 7);
      gload_lds16(Bsrc + (size_t)row * K + t * 64 + gc * 8, dst + (p * 256 + w * 64) * 8);
    }
  };
  auto compute = [&](const __bf16* Ab, const __bf16* Bb) {
    bf16x8 af[2][2], bfr[4][2];
#pragma unroll
    for (int i = 0; i < 2; ++i) {
      int m = w * 32 + i * 16 + l15;
#pragma unroll
      for (int kk = 0; kk < 2; ++kk)
        af[i][kk] = *(const bf16x8*)((const char*)Ab + m * 128 + (((kk * 4 + g4) ^ (m & 7)) << 4));
    }
#pragma unroll
    for (int j = 0; j < 4; ++j) {
      int n = j * 16 + l15;
#pragma unroll
      for (int kk = 0; kk < 2; ++kk)
        bfr[j][kk] = *(const bf16x8*)((const char*)Bb + n * 128 + (((kk * 4 + g4) ^ (n & 7)) << 4));
    }
#pragma unroll
    for (int kk = 0; kk < 2; ++kk)
#pragma unroll
      for (int i = 0; i < 2; ++i)
#pragma unroll
        for (int j = 0; j < 4; ++j)
          acc[i][j] = __builtin_amdgcn_mfma_f32_16x16x32_bf16(af[i][kk], bfr[j][kk], acc[i][j], 0, 0, 0);
  };

  issueA(0, As[0]); issueB(0, Bs[0]);
  __syncthreads();

  for (int t = 0; t < NT; t += 2) {
    issueA(t + 1, As[1]); issueB(t + 1, Bs[1]);
    compute(As[0], Bs[0]);
    __syncthreads();
    if (t + 2 < NT) { issueA(t + 2, As[0]); issueB(t + 2, Bs[0]); }
    compute(As[1], Bs[1]);
    __syncthreads();
  }

  if constexpr (MODE == 0) {
#pragma unroll
    for (int i = 0; i < 2; ++i)
#pragma unroll
      for (int j = 0; j < 4; ++j)
#pragma unroll
        for (int r = 0; r < 4; ++r) {
          size_t row = bm * 128 + w * 32 + i * 16 + g4 * 4 + r;
          size_t col = bn * 64 + j * 16 + l15;
          C[row * 4096 + col] = acc[i][j][r];
        }
  } else {
    const int nb0 = bn * 64;
    if (bn < 80) {
      __bf16* dst = (bn < 64) ? Qb : Kb;
      int ldc = (bn < 64) ? 4096 : 1024;
      int coff = (bn < 64) ? 0 : 4096;
#pragma unroll
      for (int i = 0; i < 2; ++i)
#pragma unroll
        for (int j = 0; j < 4; ++j)
#pragma unroll
          for (int r = 0; r < 4; ++r) {
            size_t row = bm * 128 + w * 32 + i * 16 + g4 * 4 + r;
            size_t col = nb0 - coff + j * 16 + l15;
            dst[row * ldc + col] = (__bf16)acc[i][j][r];
          }
    } else {
#pragma unroll
      for (int i = 0; i < 2; ++i)
#pragma unroll
        for (int j = 0; j < 4; ++j) {
          size_t n = nb0 - 5120 + j * 16 + l15;
          size_t m0 = bm * 128 + w * 32 + i * 16 + g4 * 4;
          bf16x4 v;
          v.x = (__bf16)acc[i][j][0]; v.y = (__bf16)acc[i][j][1];
          v.z = (__bf16)acc[i][j][2]; v.w = (__bf16)acc[i][j][3];
          *(bf16x4*)&Vt[n * 1024 + m0] = v;
        }
    }
  }
}

// ---------------- flash attention (round-2 proven) ----------------
__global__ __launch_bounds__(256) void k_attn(const __bf16* __restrict__ Q,
                                              const __bf16* __restrict__ Kb,
                                              const __bf16* __restrict__ Vt,
                                              __bf16* __restrict__ ctx) {
  __shared__ __align__(16) char lds_raw[65536];
  __bf16* Ks = (__bf16*)lds_raw;
  __bf16* Vs = (__bf16*)(lds_raw + 32768);

  const int h = blockIdx.y, g = h >> 2;
  const int q0 = blockIdx.x * 64;
  const int tid = threadIdx.x, w = tid >> 6, l = tid & 63;
  const int l15 = l & 15, g4 = l >> 4;
  const float scale = 0.08838834764831845f;

  bf16x8 qf[4];
  const int qrow = q0 + w * 16 + l15;
#pragma unroll
  for (int ks = 0; ks < 4; ++ks)
    qf[ks] = *(const bf16x8*)&Q[(size_t)qrow * (NH * HD) + h * HD + ks * 32 + g4 * 8];

  f32x4 acc[8];
#pragma unroll
  for (int i = 0; i < 8; ++i)
#pragma unroll
    for (int r = 0; r < 4; ++r) acc[i][r] = 0.f;
  float m_run = -__builtin_inff(), l_run = 0.f;

  const int ntiles = (q0 + 64 + 127) >> 7;
  for (int kt = 0; kt < ntiles; ++kt) {
    const int kv0 = kt * 128;
#pragma unroll
    for (int p = 0; p < 8; ++p) {
      int c = p * 256 + tid;
      int row = c >> 4, cc = c & 15;
      gload_lds16(&Kb[(size_t)(kv0 + row) * (NG * HD) + g * HD + ((cc ^ (row & 7)) << 3)],
                  &Ks[(p * 256 + w * 64) * 8]);
      gload_lds16(&Vt[(size_t)(g * HD + row) * S_LEN + kv0 + ((cc ^ (row & 7)) << 3)],
                  &Vs[(p * 256 + w * 64) * 8]);
    }
    __syncthreads();

    float sreg[8][4];
    const bool need_mask = (kv0 + 127 > q0);
#pragma unroll
    for (int tf = 0; tf < 8; ++tf) {
      f32x4 sa;
#pragma unroll
      for (int r = 0; r < 4; ++r) sa[r] = 0.f;
      int t_loc = tf * 16 + l15;
#pragma unroll
      for (int ks = 0; ks < 4; ++ks) {
        bf16x8 kf = *(const bf16x8*)((const char*)Ks + t_loc * 256 + (((ks * 4 + g4) ^ (t_loc & 7)) << 4));
        sa = __builtin_amdgcn_mfma_f32_16x16x32_bf16(kf, qf[ks], sa, 0, 0, 0);
      }
#pragma unroll
      for (int r = 0; r < 4; ++r) {
        float v = sa[r] * scale;
        if (need_mask && (kv0 + tf * 16 + g4 * 4 + r) > qrow) v = -__builtin_inff();
        sreg[tf][r] = v;
      }
    }
    float mx = -__builtin_inff();
#pragma unroll
    for (int tf = 0; tf < 8; ++tf)
#pragma unroll
      for (int r = 0; r < 4; ++r) mx = fmaxf(mx, sreg[tf][r]);
    mx = fmaxf(mx, __shfl_xor(mx, 16));
    mx = fmaxf(mx, __shfl_xor(mx, 32));
    const float m_new = fmaxf(m_run, mx);
    const float alpha = __expf(m_run - m_new);
    float ssum = 0.f;
#pragma unroll
    for (int tf = 0; tf < 8; ++tf)
#pragma unroll
      for (int r = 0; r < 4; ++r) {
        sreg[tf][r] = __expf(sreg[tf][r] - m_new);
        ssum += sreg[tf][r];
      }
    ssum += __shfl_xor(ssum, 16);
    ssum += __shfl_xor(ssum, 32);
    l_run = l_run * alpha + ssum;
    m_run = m_new;
    float ar[4];
#pragma unroll
    for (int r = 0; r < 4; ++r) ar[r] = __shfl(alpha, g4 * 4 + r);
#pragma unroll
    for (int nf = 0; nf < 8; ++nf)
#pragma unroll
      for (int r = 0; r < 4; ++r) acc[nf][r] *= ar[r];

    __syncthreads();

    char* pb = lds_raw + w * 4096;
#pragma unroll
    for (int tf = 0; tf < 8; ++tf) {
      int chunkc = 2 * tf + (g4 >> 1);
      int addr = l15 * 256 + ((chunkc ^ (l15 & 7)) << 4) + ((g4 & 1) << 3);
      *(unsigned*)(pb + addr)     = pack2bf(sreg[tf][0], sreg[tf][1]);
      *(unsigned*)(pb + addr + 4) = pack2bf(sreg[tf][2], sreg[tf][3]);
    }
    asm volatile("s_waitcnt lgkmcnt(0)" ::: "memory");
    bf16x8 pf[4];
#pragma unroll
    for (int ks = 0; ks < 4; ++ks)
      pf[ks] = *(const bf16x8*)(pb + l15 * 256 + (((ks * 4 + g4) ^ (l15 & 7)) << 4));
#pragma unroll
    for (int nf = 0; nf < 8; ++nf) {
      int d_loc = nf * 16 + l15;
#pragma unroll
      for (int ks = 0; ks < 4; ++ks) {
        bf16x8 vf = *(const bf16x8*)((const char*)Vs + d_loc * 256 + (((ks * 4 + g4) ^ (d_loc & 7)) << 4));
        acc[nf] = __builtin_amdgcn_mfma_f32_16x16x32_bf16(pf[ks], vf, acc[nf], 0, 0, 0);
      }
    }
    __syncthreads();
  }
  float li[4];
#pragma unroll
  for (int r = 0; r < 4; ++r) li[r] = 1.f / __shfl(l_run, g4 * 4 + r);
#pragma unroll
  for (int nf = 0; nf < 8; ++nf)
#pragma unroll
    for (int r = 0; r < 4; ++r) {
      size_t row = q0 + w * 16 + g4 * 4 + r;
      size_t col = (size_t)h * HD + nf * 16 + l15;
      ctx[row * (NH * HD) + col] = (__bf16)(acc[nf][r] * li[r]);
    }
}

// ---------------- host ----------------
extern "C" void kernel_launch(void* const* d_in, const int* in_sizes, int n_in,
                              void* d_out, int out_size, void* d_ws, size_t ws_size,
                              hipStream_t stream) {
  const float* x    = (const float*)d_in[0];
  const float* cosT = (const float*)d_in[2];
  const float* sinT = (const float*)d_in[3];
  const float* Wq   = (const float*)d_in[4];
  const float* Wk   = (const float*)d_in[5];
  const float* Wv   = (const float*)d_in[6];
  const float* Wo   = (const float*)d_in[7];
  float* out = (float*)d_out;

  char* ws = (char*)d_ws;
  const size_t MB = 1u << 20;
  __bf16* xb    = (__bf16*)(ws + 0);        // 8 MB : x bf16; reused as ctx after QKV
  __bf16* WqkvT = (__bf16*)(ws + 8 * MB);   // 48 MB: [Wq^T|Wk^T|Wv^T] (6144 x 4096)
  __bf16* WoT   = (__bf16*)(ws + 56 * MB);  // 32 MB: Wo^T (4096 x 4096)
  __bf16* Qb    = (__bf16*)(ws + 88 * MB);  // 8 MB : Q, roped in-place
  __bf16* Kbuf  = (__bf16*)(ws + 96 * MB);  // 2 MB : K, roped in-place
  __bf16* Vtb   = (__bf16*)(ws + 98 * MB);  // 2 MB : V^T (direct from epilogue)
  __bf16* ctxb  = (__bf16*)(ws + 0);        // aliases xb

  k_prep<<<14336, 256, 0, stream>>>(x, Wq, Wk, Wv, Wo, xb, WqkvT, WoT);

  // fused QKV: (1024 x 6144), V written transposed
  k_gemm<1><<<dim3(96, 8), 256, 0, stream>>>(xb, WqkvT, nullptr, Qb, Kbuf, Vtb);

  k_rope<<<2560, 256, 0, stream>>>(Qb, Kbuf, cosT, sinT);

  k_attn<<<dim3(16, 32), 256, 0, stream>>>(Qb, Kbuf, Vtb, ctxb);

  // out = ctx * WoT^T (1024 x 4096), f32
  k_gemm<0><<<dim3(64, 8), 256, 0, stream>>>(ctxb, WoT, out, nullptr, nullptr, nullptr);
}

// Round 7
// 217.918 us; speedup vs baseline: 1.0044x; 1.0044x over previous
//
#include <hip/hip_runtime.h>
#include <hip/hip_bf16.h>

#define S_LEN 1024
#define DIN 4096
#define NH 32
#define NG 8
#define HD 128

typedef __bf16 bf16x8 __attribute__((ext_vector_type(8)));
typedef __bf16 bf16x4 __attribute__((ext_vector_type(4)));
typedef float f32x4 __attribute__((ext_vector_type(4)));

__device__ __forceinline__ void gload_lds16(const void* g, void* l) {
  __builtin_amdgcn_global_load_lds(
      (const __attribute__((address_space(1))) unsigned int*)g,
      (__attribute__((address_space(3))) unsigned int*)l, 16, 0, 0);
}

__device__ __forceinline__ unsigned pack2bf(float a, float b) {
  union { __bf16 h[2]; unsigned u; } x;
  x.h[0] = (__bf16)a; x.h[1] = (__bf16)b;
  return x.u;
}

// ---------------- fused prep: cast x + transpose+cast all weights ----------------
// blocks [0,4096): cast x (float4 -> bf16x4).
// blocks [4096, 4096+2560): transpose strips. Strip block = 64 output rows x 256 k.
//   n-tile nt = b%160 (0-63 Wq, 64-79 Wk, 80-95 Wv, 96-159 Wo), k-tile kt = b/160.
// Phase W: read 2 coalesced f32 rows/slot (256B segments), pack k-pairs into dwords,
//   b128 LDS write at chunk' = chunk ^ (kp&7)  [round-6 verified: 0 conflicts].
// Phase R: 4 scalar b32 reads down kp (derived 2-way banks = free) ->
//   uint4 global write with n = tid>>2, cc = (tid&3)+4s: 4 consecutive lanes write
//   64B contiguous -> FULL cachelines (fixes round-6's 16B/8KB-stride writes).
__global__ __launch_bounds__(256) void k_prep(const float* __restrict__ x,
                                              const float* __restrict__ Wq,
                                              const float* __restrict__ Wk,
                                              const float* __restrict__ Wv,
                                              const float* __restrict__ Wo,
                                              __bf16* __restrict__ xb,
                                              __bf16* __restrict__ WqkvT,
                                              __bf16* __restrict__ WoT) {
  __shared__ unsigned t3[128 * 64];  // 32 KB: [kp 0..127][16 chunks][4 dwords]
  const int tid = threadIdx.x;
  int bid = blockIdx.x;
  if (bid < 4096) {
    int i = bid * 256 + tid;
    const float4 v = ((const float4*)x)[i];
    bf16x4 o;
    o.x = (__bf16)v.x; o.y = (__bf16)v.y; o.z = (__bf16)v.z; o.w = (__bf16)v.w;
    ((bf16x4*)xb)[i] = o;
    return;
  }
  bid -= 4096;
  const int nt = bid % 160, kt = bid / 160;
  const int k0 = kt * 256;
  const float* W; __bf16* WT; int N, nsrc0, nd0;
  if (nt < 64)       { W = Wq; WT = WqkvT; N = 4096; nsrc0 = nt * 64;        nd0 = nt * 64; }
  else if (nt < 80)  { W = Wk; WT = WqkvT; N = 1024; nsrc0 = (nt - 64) * 64; nd0 = nt * 64; }
  else if (nt < 96)  { W = Wv; WT = WqkvT; N = 1024; nsrc0 = (nt - 80) * 64; nd0 = nt * 64; }
  else               { W = Wo; WT = WoT;   N = 4096; nsrc0 = (nt - 96) * 64; nd0 = (nt - 96) * 64; }

  // ---- Phase W ----
#pragma unroll
  for (int p = 0; p < 8; ++p) {
    int slot = p * 256 + tid;        // [0,2048)
    int kp = slot >> 4;              // [0,128)
    int nn = (slot & 15) * 4;        // col group
    const float4 a = *(const float4*)&W[(size_t)(k0 + 2 * kp) * N + nsrc0 + nn];
    const float4 b = *(const float4*)&W[(size_t)(k0 + 2 * kp + 1) * N + nsrc0 + nn];
    int cphys = (nn >> 2) ^ (kp & 7);
    uint4 d;
    d.x = pack2bf(a.x, b.x);
    d.y = pack2bf(a.y, b.y);
    d.z = pack2bf(a.z, b.z);
    d.w = pack2bf(a.w, b.w);
    *(uint4*)&t3[kp * 64 + cphys * 4] = d;
  }
  __syncthreads();

  // ---- Phase R ----
  const int n = tid >> 2;            // output row [0,64)
#pragma unroll
  for (int s = 0; s < 8; ++s) {
    int cc = (tid & 3) + 4 * s;      // k-chunk [0,32), 8 k each
    int kp0 = 4 * cc;
    uint4 d;
    d.x = t3[(kp0 + 0) * 64 + ((((n >> 2)) ^ ((kp0 + 0) & 7)) << 2) + (n & 3)];
    d.y = t3[(kp0 + 1) * 64 + ((((n >> 2)) ^ ((kp0 + 1) & 7)) << 2) + (n & 3)];
    d.z = t3[(kp0 + 2) * 64 + ((((n >> 2)) ^ ((kp0 + 2) & 7)) << 2) + (n & 3)];
    d.w = t3[(kp0 + 3) * 64 + ((((n >> 2)) ^ ((kp0 + 3) & 7)) << 2) + (n & 3)];
    *(uint4*)&WT[(size_t)(nd0 + n) * DIN + k0 + 8 * cc] = d;
  }
}

// ---------------- RoPE, vectorized: 4 d-pairs per thread ----------------
__global__ __launch_bounds__(256) void k_rope(__bf16* __restrict__ Q, __bf16* __restrict__ Kb,
                                              const float* __restrict__ cosT,
                                              const float* __restrict__ sinT) {
  int idx = blockIdx.x * 256 + threadIdx.x;
  int d = (idx & 15) * 4;
  int row = idx >> 4;
  __bf16* p; int s;
  if (row < S_LEN * NH) { p = Q + (size_t)row * HD; s = row >> 5; }
  else { int r = row - S_LEN * NH; p = Kb + (size_t)r * HD; s = r >> 3; }
  const float4 c = *(const float4*)&cosT[s * HD + d];
  const float4 sn = *(const float4*)&sinT[s * HD + d];
  bf16x4 a = *(const bf16x4*)&p[d];
  bf16x4 b = *(const bf16x4*)&p[d + 64];
  bf16x4 oa, ob;
  oa.x = (__bf16)((float)a.x * c.x - (float)b.x * sn.x);
  oa.y = (__bf16)((float)a.y * c.y - (float)b.y * sn.y);
  oa.z = (__bf16)((float)a.z * c.z - (float)b.z * sn.z);
  oa.w = (__bf16)((float)a.w * c.w - (float)b.w * sn.w);
  ob.x = (__bf16)((float)b.x * c.x + (float)a.x * sn.x);
  ob.y = (__bf16)((float)b.y * c.y + (float)a.y * sn.y);
  ob.z = (__bf16)((float)b.z * c.z + (float)a.z * sn.z);
  ob.w = (__bf16)((float)b.w * c.w + (float)a.w * sn.w);
  *(bf16x4*)&p[d] = oa;
  *(bf16x4*)&p[d + 64] = ob;
}

// ---------------- GEMM: C(M,N) = A(M,K) * Bt(N,K)^T, bf16 in ----------------
// BM=128, BN=64, BK=64. 4 waves. Round-2 proven layout (0 bank conflicts):
// all LDS writes via global_load_lds DMA, 3-bit XOR chunk swizzle, b128 frag reads.
// Double-buffered + prefetch(t+1) issued before compute(t), 1 barrier/iter.
// MODE 0: f32 C (N=4096). MODE 1: QKV split epilogue (Q,K bf16; V written transposed).
template <int MODE>
__global__ __launch_bounds__(256, 3) void k_gemm(const __bf16* __restrict__ A,
                                                 const __bf16* __restrict__ Bt,
                                                 float* __restrict__ C,
                                                 __bf16* __restrict__ Qb,
                                                 __bf16* __restrict__ Kb,
                                                 __bf16* __restrict__ Vt) {
  __shared__ __bf16 As[2][128 * 64];
  __shared__ __bf16 Bs[2][64 * 64];
  const int bm = blockIdx.y, bn = blockIdx.x;
  const int K = DIN, NT = K / 64;

  const int tid = threadIdx.x, w = tid >> 6;
  const int l = tid & 63, l15 = l & 15, g4 = l >> 4;

  const __bf16* Asrc = A + (size_t)(bm * 128) * K;
  const __bf16* Bsrc = Bt + (size_t)(bn * 64) * K;

  f32x4 acc[2][4];
#pragma unroll
  for (int i = 0; i < 2; ++i)
#pragma unroll
    for (int j = 0; j < 4; ++j)
#pragma unroll
      for (int r = 0; r < 4; ++r) acc[i][j][r] = 0.f;

  auto issueA = [&](int t, __bf16* dst) {
#pragma unroll
    for (int p = 0; p < 4; ++p) {
      int c = p * 256 + tid;
      int row = c >> 3, gc = (c & 7) ^ (row & 7);
      gload_lds16(Asrc + (size_t)row * K + t * 64 + gc * 8, dst + (p * 256 + w * 64) * 8);
    }
  };
  auto issueB = [&](int t, __bf16* dst) {
#pragma unroll
    for (int p = 0; p < 2; ++p) {
      int c = p * 256 + tid;
      int row = c >> 3, gc = (c & 7) ^ (row & 7);
      gload_lds16(Bsrc + (size_t)row * K + t * 64 + gc * 8, dst + (p * 256 + w * 64) * 8);
    }
  };
  auto compute = [&](const __bf16* Ab, const __bf16* Bb) {
    bf16x8 af[2][2], bfr[4][2];
#pragma unroll
    for (int i = 0; i < 2; ++i) {
      int m = w * 32 + i * 16 + l15;
#pragma unroll
      for (int kk = 0; kk < 2; ++kk)
        af[i][kk] = *(const bf16x8*)((const char*)Ab + m * 128 + (((kk * 4 + g4) ^ (m & 7)) << 4));
    }
#pragma unroll
    for (int j = 0; j < 4; ++j) {
      int n = j * 16 + l15;
#pragma unroll
      for (int kk = 0; kk < 2; ++kk)
        bfr[j][kk] = *(const bf16x8*)((const char*)Bb + n * 128 + (((kk * 4 + g4) ^ (n & 7)) << 4));
    }
#pragma unroll
    for (int kk = 0; kk < 2; ++kk)
#pragma unroll
      for (int i = 0; i < 2; ++i)
#pragma unroll
        for (int j = 0; j < 4; ++j)
          acc[i][j] = __builtin_amdgcn_mfma_f32_16x16x32_bf16(af[i][kk], bfr[j][kk], acc[i][j], 0, 0, 0);
  };

  issueA(0, As[0]); issueB(0, Bs[0]);
  __syncthreads();

  for (int t = 0; t < NT; t += 2) {
    issueA(t + 1, As[1]); issueB(t + 1, Bs[1]);
    compute(As[0], Bs[0]);
    __syncthreads();
    if (t + 2 < NT) { issueA(t + 2, As[0]); issueB(t + 2, Bs[0]); }
    compute(As[1], Bs[1]);
    __syncthreads();
  }

  if constexpr (MODE == 0) {
#pragma unroll
    for (int i = 0; i < 2; ++i)
#pragma unroll
      for (int j = 0; j < 4; ++j)
#pragma unroll
        for (int r = 0; r < 4; ++r) {
          size_t row = bm * 128 + w * 32 + i * 16 + g4 * 4 + r;
          size_t col = bn * 64 + j * 16 + l15;
          C[row * 4096 + col] = acc[i][j][r];
        }
  } else {
    const int nb0 = bn * 64;
    if (bn < 80) {
      __bf16* dst = (bn < 64) ? Qb : Kb;
      int ldc = (bn < 64) ? 4096 : 1024;
      int coff = (bn < 64) ? 0 : 4096;
#pragma unroll
      for (int i = 0; i < 2; ++i)
#pragma unroll
        for (int j = 0; j < 4; ++j)
#pragma unroll
          for (int r = 0; r < 4; ++r) {
            size_t row = bm * 128 + w * 32 + i * 16 + g4 * 4 + r;
            size_t col = nb0 - coff + j * 16 + l15;
            dst[row * ldc + col] = (__bf16)acc[i][j][r];
          }
    } else {
#pragma unroll
      for (int i = 0; i < 2; ++i)
#pragma unroll
        for (int j = 0; j < 4; ++j) {
          size_t n = nb0 - 5120 + j * 16 + l15;
          size_t m0 = bm * 128 + w * 32 + i * 16 + g4 * 4;
          bf16x4 v;
          v.x = (__bf16)acc[i][j][0]; v.y = (__bf16)acc[i][j][1];
          v.z = (__bf16)acc[i][j][2]; v.w = (__bf16)acc[i][j][3];
          *(bf16x4*)&Vt[n * 1024 + m0] = v;
        }
    }
  }
}

// ---------------- flash attention (round-2 proven) ----------------
__global__ __launch_bounds__(256) void k_attn(const __bf16* __restrict__ Q,
                                              const __bf16* __restrict__ Kb,
                                              const __bf16* __restrict__ Vt,
                                              __bf16* __restrict__ ctx) {
  __shared__ __align__(16) char lds_raw[65536];
  __bf16* Ks = (__bf16*)lds_raw;
  __bf16* Vs = (__bf16*)(lds_raw + 32768);

  const int h = blockIdx.y, g = h >> 2;
  const int q0 = blockIdx.x * 64;
  const int tid = threadIdx.x, w = tid >> 6, l = tid & 63;
  const int l15 = l & 15, g4 = l >> 4;
  const float scale = 0.08838834764831845f;

  bf16x8 qf[4];
  const int qrow = q0 + w * 16 + l15;
#pragma unroll
  for (int ks = 0; ks < 4; ++ks)
    qf[ks] = *(const bf16x8*)&Q[(size_t)qrow * (NH * HD) + h * HD + ks * 32 + g4 * 8];

  f32x4 acc[8];
#pragma unroll
  for (int i = 0; i < 8; ++i)
#pragma unroll
    for (int r = 0; r < 4; ++r) acc[i][r] = 0.f;
  float m_run = -__builtin_inff(), l_run = 0.f;

  const int ntiles = (q0 + 64 + 127) >> 7;
  for (int kt = 0; kt < ntiles; ++kt) {
    const int kv0 = kt * 128;
#pragma unroll
    for (int p = 0; p < 8; ++p) {
      int c = p * 256 + tid;
      int row = c >> 4, cc = c & 15;
      gload_lds16(&Kb[(size_t)(kv0 + row) * (NG * HD) + g * HD + ((cc ^ (row & 7)) << 3)],
                  &Ks[(p * 256 + w * 64) * 8]);
      gload_lds16(&Vt[(size_t)(g * HD + row) * S_LEN + kv0 + ((cc ^ (row & 7)) << 3)],
                  &Vs[(p * 256 + w * 64) * 8]);
    }
    __syncthreads();

    float sreg[8][4];
    const bool need_mask = (kv0 + 127 > q0);
#pragma unroll
    for (int tf = 0; tf < 8; ++tf) {
      f32x4 sa;
#pragma unroll
      for (int r = 0; r < 4; ++r) sa[r] = 0.f;
      int t_loc = tf * 16 + l15;
#pragma unroll
      for (int ks = 0; ks < 4; ++ks) {
        bf16x8 kf = *(const bf16x8*)((const char*)Ks + t_loc * 256 + (((ks * 4 + g4) ^ (t_loc & 7)) << 4));
        sa = __builtin_amdgcn_mfma_f32_16x16x32_bf16(kf, qf[ks], sa, 0, 0, 0);
      }
#pragma unroll
      for (int r = 0; r < 4; ++r) {
        float v = sa[r] * scale;
        if (need_mask && (kv0 + tf * 16 + g4 * 4 + r) > qrow) v = -__builtin_inff();
        sreg[tf][r] = v;
      }
    }
    float mx = -__builtin_inff();
#pragma unroll
    for (int tf = 0; tf < 8; ++tf)
#pragma unroll
      for (int r = 0; r < 4; ++r) mx = fmaxf(mx, sreg[tf][r]);
    mx = fmaxf(mx, __shfl_xor(mx, 16));
    mx = fmaxf(mx, __shfl_xor(mx, 32));
    const float m_new = fmaxf(m_run, mx);
    const float alpha = __expf(m_run - m_new);
    float ssum = 0.f;
#pragma unroll
    for (int tf = 0; tf < 8; ++tf)
#pragma unroll
      for (int r = 0; r < 4; ++r) {
        sreg[tf][r] = __expf(sreg[tf][r] - m_new);
        ssum += sreg[tf][r];
      }
    ssum += __shfl_xor(ssum, 16);
    ssum += __shfl_xor(ssum, 32);
    l_run = l_run * alpha + ssum;
    m_run = m_new;
    float ar[4];
#pragma unroll
    for (int r = 0; r < 4; ++r) ar[r] = __shfl(alpha, g4 * 4 + r);
#pragma unroll
    for (int nf = 0; nf < 8; ++nf)
#pragma unroll
      for (int r = 0; r < 4; ++r) acc[nf][r] *= ar[r];

    __syncthreads();

    char* pb = lds_raw + w * 4096;
#pragma unroll
    for (int tf = 0; tf < 8; ++tf) {
      int chunkc = 2 * tf + (g4 >> 1);
      int addr = l15 * 256 + ((chunkc ^ (l15 & 7)) << 4) + ((g4 & 1) << 3);
      *(unsigned*)(pb + addr)     = pack2bf(sreg[tf][0], sreg[tf][1]);
      *(unsigned*)(pb + addr + 4) = pack2bf(sreg[tf][2], sreg[tf][3]);
    }
    asm volatile("s_waitcnt lgkmcnt(0)" ::: "memory");
    bf16x8 pf[4];
#pragma unroll
    for (int ks = 0; ks < 4; ++ks)
      pf[ks] = *(const bf16x8*)(pb + l15 * 256 + (((ks * 4 + g4) ^ (l15 & 7)) << 4));
#pragma unroll
    for (int nf = 0; nf < 8; ++nf) {
      int d_loc = nf * 16 + l15;
#pragma unroll
      for (int ks = 0; ks < 4; ++ks) {
        bf16x8 vf = *(const bf16x8*)((const char*)Vs + d_loc * 256 + (((ks * 4 + g4) ^ (d_loc & 7)) << 4));
        acc[nf] = __builtin_amdgcn_mfma_f32_16x16x32_bf16(pf[ks], vf, acc[nf], 0, 0, 0);
      }
    }
    __syncthreads();
  }
  float li[4];
#pragma unroll
  for (int r = 0; r < 4; ++r) li[r] = 1.f / __shfl(l_run, g4 * 4 + r);
#pragma unroll
  for (int nf = 0; nf < 8; ++nf)
#pragma unroll
    for (int r = 0; r < 4; ++r) {
      size_t row = q0 + w * 16 + g4 * 4 + r;
      size_t col = (size_t)h * HD + nf * 16 + l15;
      ctx[row * (NH * HD) + col] = (__bf16)(acc[nf][r] * li[r]);
    }
}

// ---------------- host ----------------
extern "C" void kernel_launch(void* const* d_in, const int* in_sizes, int n_in,
                              void* d_out, int out_size, void* d_ws, size_t ws_size,
                              hipStream_t stream) {
  const float* x    = (const float*)d_in[0];
  const float* cosT = (const float*)d_in[2];
  const float* sinT = (const float*)d_in[3];
  const float* Wq   = (const float*)d_in[4];
  const float* Wk   = (const float*)d_in[5];
  const float* Wv   = (const float*)d_in[6];
  const float* Wo   = (const float*)d_in[7];
  float* out = (float*)d_out;

  char* ws = (char*)d_ws;
  const size_t MB = 1u << 20;
  __bf16* xb    = (__bf16*)(ws + 0);        // 8 MB : x bf16; reused as ctx after QKV
  __bf16* WqkvT = (__bf16*)(ws + 8 * MB);   // 48 MB: [Wq^T|Wk^T|Wv^T] (6144 x 4096)
  __bf16* WoT   = (__bf16*)(ws + 56 * MB);  // 32 MB: Wo^T (4096 x 4096)
  __bf16* Qb    = (__bf16*)(ws + 88 * MB);  // 8 MB : Q, roped in-place
  __bf16* Kbuf  = (__bf16*)(ws + 96 * MB);  // 2 MB : K, roped in-place
  __bf16* Vtb   = (__bf16*)(ws + 98 * MB);  // 2 MB : V^T (direct from epilogue)
  __bf16* ctxb  = (__bf16*)(ws + 0);        // aliases xb

  // 4096 cast blocks + 160 n-strips x 16 k-tiles = 6656
  k_prep<<<4096 + 160 * 16, 256, 0, stream>>>(x, Wq, Wk, Wv, Wo, xb, WqkvT, WoT);

  // fused QKV: (1024 x 6144), V written transposed
  k_gemm<1><<<dim3(96, 8), 256, 0, stream>>>(xb, WqkvT, nullptr, Qb, Kbuf, Vtb);

  k_rope<<<2560, 256, 0, stream>>>(Qb, Kbuf, cosT, sinT);

  k_attn<<<dim3(16, 32), 256, 0, stream>>>(Qb, Kbuf, Vtb, ctxb);

  // out = ctx * WoT^T (1024 x 4096), f32
  k_gemm<0><<<dim3(64, 8), 256, 0, stream>>>(ctxb, WoT, out, nullptr, nullptr, nullptr);
}

// Round 8
// 214.877 us; speedup vs baseline: 1.0186x; 1.0142x over previous
//
#include <hip/hip_runtime.h>
#include <hip/hip_bf16.h>

#define S_LEN 1024
#define DIN 4096
#define NH 32
#define NG 8
#define HD 128

typedef __bf16 bf16x8 __attribute__((ext_vector_type(8)));
typedef __bf16 bf16x4 __attribute__((ext_vector_type(4)));
typedef float f32x4 __attribute__((ext_vector_type(4)));

__device__ __forceinline__ void gload_lds16(const void* g, void* l) {
  __builtin_amdgcn_global_load_lds(
      (const __attribute__((address_space(1))) unsigned int*)g,
      (__attribute__((address_space(3))) unsigned int*)l, 16, 0, 0);
}

__device__ __forceinline__ unsigned pack2bf(float a, float b) {
  union { __bf16 h[2]; unsigned u; } x;
  x.h[0] = (__bf16)a; x.h[1] = (__bf16)b;
  return x.u;
}

// ---------------- fused prep: cast x + transpose+cast all weights ----------------
// blocks [0,4096): cast x (float4 -> bf16x4).
// blocks [4096, 4096+2560): transpose. Tile = 256 output rows (n) x 64 k.
//   nt = b%40 (0-15 Wq, 16-19 Wk, 20-23 Wv, 24-39 Wo), kt = b/40.
// WHY this shape (r5-r7 post-mortem): three LDS/write variants all hit ~84us ->
//   bound is the 256B-per-16KB-row READ pattern (DRAM channel/page granularity).
//   Here each wave reads 1024B contiguous per row visit (4x), and each store
//   instruction writes 8 FULL 128B cachelines.
// LDS: dword tile [kp 0..31][chunk c 0..63][j 0..3], chunk swizzled c^=((kp>>1)&7)
//   (involution on both sides; residual 2-4way read conflicts - irrelevant here).
__global__ __launch_bounds__(256) void k_prep(const float* __restrict__ x,
                                              const float* __restrict__ Wq,
                                              const float* __restrict__ Wk,
                                              const float* __restrict__ Wv,
                                              const float* __restrict__ Wo,
                                              __bf16* __restrict__ xb,
                                              __bf16* __restrict__ WqkvT,
                                              __bf16* __restrict__ WoT) {
  __shared__ unsigned t3[32 * 256];  // 32 KB
  const int tid = threadIdx.x;
  int bid = blockIdx.x;
  if (bid < 4096) {
    int i = bid * 256 + tid;
    const float4 v = ((const float4*)x)[i];
    bf16x4 o;
    o.x = (__bf16)v.x; o.y = (__bf16)v.y; o.z = (__bf16)v.z; o.w = (__bf16)v.w;
    ((bf16x4*)xb)[i] = o;
    return;
  }
  bid -= 4096;
  const int nt = bid % 40, kt = bid / 40;
  const int k0 = kt * 64;
  const float* W; __bf16* WT; int N, nsrc0, nd0;
  if (nt < 16)       { W = Wq; WT = WqkvT; N = 4096; nsrc0 = nt * 256;        nd0 = nt * 256; }
  else if (nt < 20)  { W = Wk; WT = WqkvT; N = 1024; nsrc0 = (nt - 16) * 256; nd0 = 4096 + (nt - 16) * 256; }
  else if (nt < 24)  { W = Wv; WT = WqkvT; N = 1024; nsrc0 = (nt - 20) * 256; nd0 = 5120 + (nt - 20) * 256; }
  else               { W = Wo; WT = WoT;   N = 4096; nsrc0 = (nt - 24) * 256; nd0 = (nt - 24) * 256; }

  // ---- Phase W: per wave, row-pair as 2 x 1024B contiguous loads ----
#pragma unroll
  for (int p = 0; p < 8; ++p) {
    int s = p * 256 + tid;           // [0,2048)
    int kp = s >> 6;                 // k-pair row [0,32)
    int nq = s & 63;                 // chunk (4 cols) [0,64)
    const float* src = &W[(size_t)(k0 + 2 * kp) * N + nsrc0 + 4 * nq];
    const float4 a = *(const float4*)src;
    const float4 b = *(const float4*)(src + N);
    int cphys = nq ^ ((kp >> 1) & 7);
    uint4 d;
    d.x = pack2bf(a.x, b.x);
    d.y = pack2bf(a.y, b.y);
    d.z = pack2bf(a.z, b.z);
    d.w = pack2bf(a.w, b.w);
    *(uint4*)&t3[kp * 256 + cphys * 4] = d;
  }
  __syncthreads();

  // ---- Phase R: 8 lanes per output row; one full 128B line per row-store ----
#pragma unroll
  for (int it = 0; it < 8; ++it) {
    int n = it * 32 + (tid >> 3);    // output row [0,256)
    int u = tid & 7;                 // uint4 idx: k = 8u..8u+7, kp = 4u..4u+3
    int nq = n >> 2, j = n & 3;
    uint4 d;
    d.x = t3[(4 * u + 0) * 256 + ((nq ^ (((4 * u + 0) >> 1) & 7)) << 2) + j];
    d.y = t3[(4 * u + 1) * 256 + ((nq ^ (((4 * u + 1) >> 1) & 7)) << 2) + j];
    d.z = t3[(4 * u + 2) * 256 + ((nq ^ (((4 * u + 2) >> 1) & 7)) << 2) + j];
    d.w = t3[(4 * u + 3) * 256 + ((nq ^ (((4 * u + 3) >> 1) & 7)) << 2) + j];
    *(uint4*)&WT[(size_t)(nd0 + n) * DIN + k0 + 8 * u] = d;
  }
}

// ---------------- RoPE, vectorized: 4 d-pairs per thread ----------------
__global__ __launch_bounds__(256) void k_rope(__bf16* __restrict__ Q, __bf16* __restrict__ Kb,
                                              const float* __restrict__ cosT,
                                              const float* __restrict__ sinT) {
  int idx = blockIdx.x * 256 + threadIdx.x;
  int d = (idx & 15) * 4;
  int row = idx >> 4;
  __bf16* p; int s;
  if (row < S_LEN * NH) { p = Q + (size_t)row * HD; s = row >> 5; }
  else { int r = row - S_LEN * NH; p = Kb + (size_t)r * HD; s = r >> 3; }
  const float4 c = *(const float4*)&cosT[s * HD + d];
  const float4 sn = *(const float4*)&sinT[s * HD + d];
  bf16x4 a = *(const bf16x4*)&p[d];
  bf16x4 b = *(const bf16x4*)&p[d + 64];
  bf16x4 oa, ob;
  oa.x = (__bf16)((float)a.x * c.x - (float)b.x * sn.x);
  oa.y = (__bf16)((float)a.y * c.y - (float)b.y * sn.y);
  oa.z = (__bf16)((float)a.z * c.z - (float)b.z * sn.z);
  oa.w = (__bf16)((float)a.w * c.w - (float)b.w * sn.w);
  ob.x = (__bf16)((float)b.x * c.x + (float)a.x * sn.x);
  ob.y = (__bf16)((float)b.y * c.y + (float)a.y * sn.y);
  ob.z = (__bf16)((float)b.z * c.z + (float)a.z * sn.z);
  ob.w = (__bf16)((float)b.w * c.w + (float)a.w * sn.w);
  *(bf16x4*)&p[d] = oa;
  *(bf16x4*)&p[d + 64] = ob;
}

// ---------------- GEMM: C(M,N) = A(M,K) * Bt(N,K)^T, bf16 in ----------------
// BM=128, BN=64, BK=64. 4 waves. Round-2 proven layout (0 bank conflicts):
// all LDS writes via global_load_lds DMA, 3-bit XOR chunk swizzle, b128 frag reads.
// Double-buffered + prefetch(t+1) issued before compute(t), 1 barrier/iter.
// MODE 0: f32 C (N=4096). MODE 1: QKV split epilogue (Q,K bf16; V written transposed).
template <int MODE>
__global__ __launch_bounds__(256, 3) void k_gemm(const __bf16* __restrict__ A,
                                                 const __bf16* __restrict__ Bt,
                                                 float* __restrict__ C,
                                                 __bf16* __restrict__ Qb,
                                                 __bf16* __restrict__ Kb,
                                                 __bf16* __restrict__ Vt) {
  __shared__ __bf16 As[2][128 * 64];
  __shared__ __bf16 Bs[2][64 * 64];
  const int bm = blockIdx.y, bn = blockIdx.x;
  const int K = DIN, NT = K / 64;

  const int tid = threadIdx.x, w = tid >> 6;
  const int l = tid & 63, l15 = l & 15, g4 = l >> 4;

  const __bf16* Asrc = A + (size_t)(bm * 128) * K;
  const __bf16* Bsrc = Bt + (size_t)(bn * 64) * K;

  f32x4 acc[2][4];
#pragma unroll
  for (int i = 0; i < 2; ++i)
#pragma unroll
    for (int j = 0; j < 4; ++j)
#pragma unroll
      for (int r = 0; r < 4; ++r) acc[i][j][r] = 0.f;

  auto issueA = [&](int t, __bf16* dst) {
#pragma unroll
    for (int p = 0; p < 4; ++p) {
      int c = p * 256 + tid;
      int row = c >> 3, gc = (c & 7) ^ (row & 7);
      gload_lds16(Asrc + (size_t)row * K + t * 64 + gc * 8, dst + (p * 256 + w * 64) * 8);
    }
  };
  auto issueB = [&](int t, __bf16* dst) {
#pragma unroll
    for (int p = 0; p < 2; ++p) {
      int c = p * 256 + tid;
      int row = c >> 3, gc = (c & 7) ^ (row & 7);
      gload_lds16(Bsrc + (size_t)row * K + t * 64 + gc * 8, dst + (p * 256 + w * 64) * 8);
    }
  };
  auto compute = [&](const __bf16* Ab, const __bf16* Bb) {
    bf16x8 af[2][2], bfr[4][2];
#pragma unroll
    for (int i = 0; i < 2; ++i) {
      int m = w * 32 + i * 16 + l15;
#pragma unroll
      for (int kk = 0; kk < 2; ++kk)
        af[i][kk] = *(const bf16x8*)((const char*)Ab + m * 128 + (((kk * 4 + g4) ^ (m & 7)) << 4));
    }
#pragma unroll
    for (int j = 0; j < 4; ++j) {
      int n = j * 16 + l15;
#pragma unroll
      for (int kk = 0; kk < 2; ++kk)
        bfr[j][kk] = *(const bf16x8*)((const char*)Bb + n * 128 + (((kk * 4 + g4) ^ (n & 7)) << 4));
    }
#pragma unroll
    for (int kk = 0; kk < 2; ++kk)
#pragma unroll
      for (int i = 0; i < 2; ++i)
#pragma unroll
        for (int j = 0; j < 4; ++j)
          acc[i][j] = __builtin_amdgcn_mfma_f32_16x16x32_bf16(af[i][kk], bfr[j][kk], acc[i][j], 0, 0, 0);
  };

  issueA(0, As[0]); issueB(0, Bs[0]);
  __syncthreads();

  for (int t = 0; t < NT; t += 2) {
    issueA(t + 1, As[1]); issueB(t + 1, Bs[1]);
    compute(As[0], Bs[0]);
    __syncthreads();
    if (t + 2 < NT) { issueA(t + 2, As[0]); issueB(t + 2, Bs[0]); }
    compute(As[1], Bs[1]);
    __syncthreads();
  }

  if constexpr (MODE == 0) {
#pragma unroll
    for (int i = 0; i < 2; ++i)
#pragma unroll
      for (int j = 0; j < 4; ++j)
#pragma unroll
        for (int r = 0; r < 4; ++r) {
          size_t row = bm * 128 + w * 32 + i * 16 + g4 * 4 + r;
          size_t col = bn * 64 + j * 16 + l15;
          C[row * 4096 + col] = acc[i][j][r];
        }
  } else {
    const int nb0 = bn * 64;
    if (bn < 80) {
      __bf16* dst = (bn < 64) ? Qb : Kb;
      int ldc = (bn < 64) ? 4096 : 1024;
      int coff = (bn < 64) ? 0 : 4096;
#pragma unroll
      for (int i = 0; i < 2; ++i)
#pragma unroll
        for (int j = 0; j < 4; ++j)
#pragma unroll
          for (int r = 0; r < 4; ++r) {
            size_t row = bm * 128 + w * 32 + i * 16 + g4 * 4 + r;
            size_t col = nb0 - coff + j * 16 + l15;
            dst[row * ldc + col] = (__bf16)acc[i][j][r];
          }
    } else {
#pragma unroll
      for (int i = 0; i < 2; ++i)
#pragma unroll
        for (int j = 0; j < 4; ++j) {
          size_t n = nb0 - 5120 + j * 16 + l15;
          size_t m0 = bm * 128 + w * 32 + i * 16 + g4 * 4;
          bf16x4 v;
          v.x = (__bf16)acc[i][j][0]; v.y = (__bf16)acc[i][j][1];
          v.z = (__bf16)acc[i][j][2]; v.w = (__bf16)acc[i][j][3];
          *(bf16x4*)&Vt[n * 1024 + m0] = v;
        }
    }
  }
}

// ---------------- flash attention (round-2 proven) ----------------
__global__ __launch_bounds__(256) void k_attn(const __bf16* __restrict__ Q,
                                              const __bf16* __restrict__ Kb,
                                              const __bf16* __restrict__ Vt,
                                              __bf16* __restrict__ ctx) {
  __shared__ __align__(16) char lds_raw[65536];
  __bf16* Ks = (__bf16*)lds_raw;
  __bf16* Vs = (__bf16*)(lds_raw + 32768);

  const int h = blockIdx.y, g = h >> 2;
  const int q0 = blockIdx.x * 64;
  const int tid = threadIdx.x, w = tid >> 6, l = tid & 63;
  const int l15 = l & 15, g4 = l >> 4;
  const float scale = 0.08838834764831845f;

  bf16x8 qf[4];
  const int qrow = q0 + w * 16 + l15;
#pragma unroll
  for (int ks = 0; ks < 4; ++ks)
    qf[ks] = *(const bf16x8*)&Q[(size_t)qrow * (NH * HD) + h * HD + ks * 32 + g4 * 8];

  f32x4 acc[8];
#pragma unroll
  for (int i = 0; i < 8; ++i)
#pragma unroll
    for (int r = 0; r < 4; ++r) acc[i][r] = 0.f;
  float m_run = -__builtin_inff(), l_run = 0.f;

  const int ntiles = (q0 + 64 + 127) >> 7;
  for (int kt = 0; kt < ntiles; ++kt) {
    const int kv0 = kt * 128;
#pragma unroll
    for (int p = 0; p < 8; ++p) {
      int c = p * 256 + tid;
      int row = c >> 4, cc = c & 15;
      gload_lds16(&Kb[(size_t)(kv0 + row) * (NG * HD) + g * HD + ((cc ^ (row & 7)) << 3)],
                  &Ks[(p * 256 + w * 64) * 8]);
      gload_lds16(&Vt[(size_t)(g * HD + row) * S_LEN + kv0 + ((cc ^ (row & 7)) << 3)],
                  &Vs[(p * 256 + w * 64) * 8]);
    }
    __syncthreads();

    float sreg[8][4];
    const bool need_mask = (kv0 + 127 > q0);
#pragma unroll
    for (int tf = 0; tf < 8; ++tf) {
      f32x4 sa;
#pragma unroll
      for (int r = 0; r < 4; ++r) sa[r] = 0.f;
      int t_loc = tf * 16 + l15;
#pragma unroll
      for (int ks = 0; ks < 4; ++ks) {
        bf16x8 kf = *(const bf16x8*)((const char*)Ks + t_loc * 256 + (((ks * 4 + g4) ^ (t_loc & 7)) << 4));
        sa = __builtin_amdgcn_mfma_f32_16x16x32_bf16(kf, qf[ks], sa, 0, 0, 0);
      }
#pragma unroll
      for (int r = 0; r < 4; ++r) {
        float v = sa[r] * scale;
        if (need_mask && (kv0 + tf * 16 + g4 * 4 + r) > qrow) v = -__builtin_inff();
        sreg[tf][r] = v;
      }
    }
    float mx = -__builtin_inff();
#pragma unroll
    for (int tf = 0; tf < 8; ++tf)
#pragma unroll
      for (int r = 0; r < 4; ++r) mx = fmaxf(mx, sreg[tf][r]);
    mx = fmaxf(mx, __shfl_xor(mx, 16));
    mx = fmaxf(mx, __shfl_xor(mx, 32));
    const float m_new = fmaxf(m_run, mx);
    const float alpha = __expf(m_run - m_new);
    float ssum = 0.f;
#pragma unroll
    for (int tf = 0; tf < 8; ++tf)
#pragma unroll
      for (int r = 0; r < 4; ++r) {
        sreg[tf][r] = __expf(sreg[tf][r] - m_new);
        ssum += sreg[tf][r];
      }
    ssum += __shfl_xor(ssum, 16);
    ssum += __shfl_xor(ssum, 32);
    l_run = l_run * alpha + ssum;
    m_run = m_new;
    float ar[4];
#pragma unroll
    for (int r = 0; r < 4; ++r) ar[r] = __shfl(alpha, g4 * 4 + r);
#pragma unroll
    for (int nf = 0; nf < 8; ++nf)
#pragma unroll
      for (int r = 0; r < 4; ++r) acc[nf][r] *= ar[r];

    __syncthreads();

    char* pb = lds_raw + w * 4096;
#pragma unroll
    for (int tf = 0; tf < 8; ++tf) {
      int chunkc = 2 * tf + (g4 >> 1);
      int addr = l15 * 256 + ((chunkc ^ (l15 & 7)) << 4) + ((g4 & 1) << 3);
      *(unsigned*)(pb + addr)     = pack2bf(sreg[tf][0], sreg[tf][1]);
      *(unsigned*)(pb + addr + 4) = pack2bf(sreg[tf][2], sreg[tf][3]);
    }
    asm volatile("s_waitcnt lgkmcnt(0)" ::: "memory");
    bf16x8 pf[4];
#pragma unroll
    for (int ks = 0; ks < 4; ++ks)
      pf[ks] = *(const bf16x8*)(pb + l15 * 256 + (((ks * 4 + g4) ^ (l15 & 7)) << 4));
#pragma unroll
    for (int nf = 0; nf < 8; ++nf) {
      int d_loc = nf * 16 + l15;
#pragma unroll
      for (int ks = 0; ks < 4; ++ks) {
        bf16x8 vf = *(const bf16x8*)((const char*)Vs + d_loc * 256 + (((ks * 4 + g4) ^ (d_loc & 7)) << 4));
        acc[nf] = __builtin_amdgcn_mfma_f32_16x16x32_bf16(pf[ks], vf, acc[nf], 0, 0, 0);
      }
    }
    __syncthreads();
  }
  float li[4];
#pragma unroll
  for (int r = 0; r < 4; ++r) li[r] = 1.f / __shfl(l_run, g4 * 4 + r);
#pragma unroll
  for (int nf = 0; nf < 8; ++nf)
#pragma unroll
    for (int r = 0; r < 4; ++r) {
      size_t row = q0 + w * 16 + g4 * 4 + r;
      size_t col = (size_t)h * HD + nf * 16 + l15;
      ctx[row * (NH * HD) + col] = (__bf16)(acc[nf][r] * li[r]);
    }
}

// ---------------- host ----------------
extern "C" void kernel_launch(void* const* d_in, const int* in_sizes, int n_in,
                              void* d_out, int out_size, void* d_ws, size_t ws_size,
                              hipStream_t stream) {
  const float* x    = (const float*)d_in[0];
  const float* cosT = (const float*)d_in[2];
  const float* sinT = (const float*)d_in[3];
  const float* Wq   = (const float*)d_in[4];
  const float* Wk   = (const float*)d_in[5];
  const float* Wv   = (const float*)d_in[6];
  const float* Wo   = (const float*)d_in[7];
  float* out = (float*)d_out;

  char* ws = (char*)d_ws;
  const size_t MB = 1u << 20;
  __bf16* xb    = (__bf16*)(ws + 0);        // 8 MB : x bf16; reused as ctx after QKV
  __bf16* WqkvT = (__bf16*)(ws + 8 * MB);   // 48 MB: [Wq^T|Wk^T|Wv^T] (6144 x 4096)
  __bf16* WoT   = (__bf16*)(ws + 56 * MB);  // 32 MB: Wo^T (4096 x 4096)
  __bf16* Qb    = (__bf16*)(ws + 88 * MB);  // 8 MB : Q, roped in-place
  __bf16* Kbuf  = (__bf16*)(ws + 96 * MB);  // 2 MB : K, roped in-place
  __bf16* Vtb   = (__bf16*)(ws + 98 * MB);  // 2 MB : V^T (direct from epilogue)
  __bf16* ctxb  = (__bf16*)(ws + 0);        // aliases xb

  // 4096 cast blocks + 40 n-strips x 64 k-tiles = 2560 transpose blocks
  k_prep<<<4096 + 2560, 256, 0, stream>>>(x, Wq, Wk, Wv, Wo, xb, WqkvT, WoT);

  // fused QKV: (1024 x 6144), V written transposed
  k_gemm<1><<<dim3(96, 8), 256, 0, stream>>>(xb, WqkvT, nullptr, Qb, Kbuf, Vtb);

  k_rope<<<2560, 256, 0, stream>>>(Qb, Kbuf, cosT, sinT);

  k_attn<<<dim3(16, 32), 256, 0, stream>>>(Qb, Kbuf, Vtb, ctxb);

  // out = ctx * WoT^T (1024 x 4096), f32
  k_gemm<0><<<dim3(64, 8), 256, 0, stream>>>(ctxb, WoT, out, nullptr, nullptr, nullptr);
}

// Round 9
// 212.126 us; speedup vs baseline: 1.0318x; 1.0130x over previous
//
#include <hip/hip_runtime.h>
#include <hip/hip_bf16.h>

#define S_LEN 1024
#define DIN 4096
#define NH 32
#define NG 8
#define HD 128

typedef __bf16 bf16x8 __attribute__((ext_vector_type(8)));
typedef __bf16 bf16x4 __attribute__((ext_vector_type(4)));
typedef float f32x4 __attribute__((ext_vector_type(4)));

__device__ __forceinline__ void gload_lds16(const void* g, void* l) {
  __builtin_amdgcn_global_load_lds(
      (const __attribute__((address_space(1))) unsigned int*)g,
      (__attribute__((address_space(3))) unsigned int*)l, 16, 0, 0);
}

__device__ __forceinline__ unsigned pack2bf(float a, float b) {
  union { __bf16 h[2]; unsigned u; } x;
  x.h[0] = (__bf16)a; x.h[1] = (__bf16)b;
  return x.u;
}

// ---------------- fused prep: cast x + transpose+cast weights into TILED B ----------------
// blocks [0,4096): cast x (float4 -> bf16x4).
// blocks [4096, 4096+2560): transpose. Block tile = 256 output rows (n) x 64 k.
//   nt = b%40 (0-15 Wq, 16-19 Wk, 20-23 Wv, 24-39 Wo), kt = b/40.
// OUTPUT LAYOUT (r8 post-mortem: 4 transpose variants all ~80us; invariant was
//   <=256B write windows at 8KB row stride -> channel-serialized writes):
//   B is stored TILED: 64x64 bf16 tiles (8KB), tile (tn,tk) at (tn*64+tk)*4096,
//   internal order = the GEMM's LDS chunk order: chunk c (16B) holds
//   row = c>>3, k-chunk lc = (c&7)^(row&7). Each block writes 4 tiles = 32KB
//   FULLY SEQUENTIAL (4KB contiguous per wave-iteration). GEMM issueB becomes a
//   linear 8KB copy; compute-side fragment reads unchanged (proven round-2).
__global__ __launch_bounds__(256) void k_prep(const float* __restrict__ x,
                                              const float* __restrict__ Wq,
                                              const float* __restrict__ Wk,
                                              const float* __restrict__ Wv,
                                              const float* __restrict__ Wo,
                                              __bf16* __restrict__ xb,
                                              __bf16* __restrict__ WqkvT,
                                              __bf16* __restrict__ WoT) {
  __shared__ unsigned t3[32 * 256];  // 32 KB
  const int tid = threadIdx.x;
  int bid = blockIdx.x;
  if (bid < 4096) {
    int i = bid * 256 + tid;
    const float4 v = ((const float4*)x)[i];
    bf16x4 o;
    o.x = (__bf16)v.x; o.y = (__bf16)v.y; o.z = (__bf16)v.z; o.w = (__bf16)v.w;
    ((bf16x4*)xb)[i] = o;
    return;
  }
  bid -= 4096;
  const int nt = bid % 40, kt = bid / 40;
  const int k0 = kt * 64;
  const float* W; __bf16* WT; int N, nsrc0, tn0;
  if (nt < 16)       { W = Wq; WT = WqkvT; N = 4096; nsrc0 = nt * 256;        tn0 = nt * 4; }
  else if (nt < 20)  { W = Wk; WT = WqkvT; N = 1024; nsrc0 = (nt - 16) * 256; tn0 = 64 + (nt - 16) * 4; }
  else if (nt < 24)  { W = Wv; WT = WqkvT; N = 1024; nsrc0 = (nt - 20) * 256; tn0 = 80 + (nt - 20) * 4; }
  else               { W = Wo; WT = WoT;   N = 4096; nsrc0 = (nt - 24) * 256; tn0 = (nt - 24) * 4; }

  // ---- Phase W: per wave, row-pair as 2 x 1024B contiguous loads ----
#pragma unroll
  for (int p = 0; p < 8; ++p) {
    int s = p * 256 + tid;           // [0,2048)
    int kp = s >> 6;                 // k-pair row [0,32)
    int nq = s & 63;                 // chunk (4 cols) [0,64)
    const float* src = &W[(size_t)(k0 + 2 * kp) * N + nsrc0 + 4 * nq];
    const float4 a = *(const float4*)src;
    const float4 b = *(const float4*)(src + N);
    int cphys = nq ^ ((kp >> 1) & 7);
    uint4 d;
    d.x = pack2bf(a.x, b.x);
    d.y = pack2bf(a.y, b.y);
    d.z = pack2bf(a.z, b.z);
    d.w = pack2bf(a.w, b.w);
    *(uint4*)&t3[kp * 256 + cphys * 4] = d;
  }
  __syncthreads();

  // ---- Phase R: gather per 16B chunk, write tiles FULLY SEQUENTIALLY ----
#pragma unroll
  for (int it = 0; it < 8; ++it) {
    int slot = it * 256 + tid;       // [0,2048)
    int ts = slot >> 9;              // sub-tile [0,4)
    int c = slot & 511;              // chunk within tile [0,512)
    int row = c >> 3;                // n within tile [0,64)
    int lc = (c & 7) ^ (row & 7);    // logical k-chunk (GEMM LDS swizzle baked in)
    int n = ts * 64 + row;           // n within block [0,256)
    int nq = n >> 2, j = n & 3;
    int kp0 = 4 * lc;
    uint4 d;
    d.x = t3[(kp0 + 0) * 256 + ((nq ^ (((kp0 + 0) >> 1) & 7)) << 2) + j];
    d.y = t3[(kp0 + 1) * 256 + ((nq ^ (((kp0 + 1) >> 1) & 7)) << 2) + j];
    d.z = t3[(kp0 + 2) * 256 + ((nq ^ (((kp0 + 2) >> 1) & 7)) << 2) + j];
    d.w = t3[(kp0 + 3) * 256 + ((nq ^ (((kp0 + 3) >> 1) & 7)) << 2) + j];
    *(uint4*)&WT[(((size_t)tn0 + ts) * 64 + kt) * 4096 + (size_t)c * 8] = d;
  }
}

// ---------------- RoPE, vectorized: 4 d-pairs per thread ----------------
__global__ __launch_bounds__(256) void k_rope(__bf16* __restrict__ Q, __bf16* __restrict__ Kb,
                                              const float* __restrict__ cosT,
                                              const float* __restrict__ sinT) {
  int idx = blockIdx.x * 256 + threadIdx.x;
  int d = (idx & 15) * 4;
  int row = idx >> 4;
  __bf16* p; int s;
  if (row < S_LEN * NH) { p = Q + (size_t)row * HD; s = row >> 5; }
  else { int r = row - S_LEN * NH; p = Kb + (size_t)r * HD; s = r >> 3; }
  const float4 c = *(const float4*)&cosT[s * HD + d];
  const float4 sn = *(const float4*)&sinT[s * HD + d];
  bf16x4 a = *(const bf16x4*)&p[d];
  bf16x4 b = *(const bf16x4*)&p[d + 64];
  bf16x4 oa, ob;
  oa.x = (__bf16)((float)a.x * c.x - (float)b.x * sn.x);
  oa.y = (__bf16)((float)a.y * c.y - (float)b.y * sn.y);
  oa.z = (__bf16)((float)a.z * c.z - (float)b.z * sn.z);
  oa.w = (__bf16)((float)a.w * c.w - (float)b.w * sn.w);
  ob.x = (__bf16)((float)b.x * c.x + (float)a.x * sn.x);
  ob.y = (__bf16)((float)b.y * c.y + (float)a.y * sn.y);
  ob.z = (__bf16)((float)b.z * c.z + (float)a.z * sn.z);
  ob.w = (__bf16)((float)b.w * c.w + (float)a.w * sn.w);
  *(bf16x4*)&p[d] = oa;
  *(bf16x4*)&p[d + 64] = ob;
}

// ---------------- GEMM: C(M,N) = A(M,K) * B^T, B in TILED layout ----------------
// BM=128, BN=64, BK=64. 4 waves. A: row-major bf16, DMA-staged with XOR chunk
// swizzle (round-2 proven). B: tiled 8KB tiles already in LDS chunk order ->
// issueB is a pure linear copy. Compute-side reads unchanged.
// Double-buffered, prefetch t+1 before compute t.
// MODE 0: f32 C (N=4096). MODE 1: QKV split epilogue (Q,K bf16; V transposed).
template <int MODE>
__global__ __launch_bounds__(256, 3) void k_gemm(const __bf16* __restrict__ A,
                                                 const __bf16* __restrict__ Bt,
                                                 float* __restrict__ C,
                                                 __bf16* __restrict__ Qb,
                                                 __bf16* __restrict__ Kb,
                                                 __bf16* __restrict__ Vt) {
  __shared__ __bf16 As[2][128 * 64];
  __shared__ __bf16 Bs[2][64 * 64];
  const int bm = blockIdx.y, bn = blockIdx.x;
  const int K = DIN, NT = K / 64;

  const int tid = threadIdx.x, w = tid >> 6;
  const int l = tid & 63, l15 = l & 15, g4 = l >> 4;

  const __bf16* Asrc = A + (size_t)(bm * 128) * K;
  const __bf16* Bsrc = Bt + (size_t)bn * 64 * 4096;  // bn-th row of 64 tiles

  f32x4 acc[2][4];
#pragma unroll
  for (int i = 0; i < 2; ++i)
#pragma unroll
    for (int j = 0; j < 4; ++j)
#pragma unroll
      for (int r = 0; r < 4; ++r) acc[i][j][r] = 0.f;

  auto issueA = [&](int t, __bf16* dst) {
#pragma unroll
    for (int p = 0; p < 4; ++p) {
      int c = p * 256 + tid;
      int row = c >> 3, gc = (c & 7) ^ (row & 7);
      gload_lds16(Asrc + (size_t)row * K + t * 64 + gc * 8, dst + (p * 256 + w * 64) * 8);
    }
  };
  auto issueB = [&](int t, __bf16* dst) {
    const __bf16* tile = Bsrc + (size_t)t * 4096;
#pragma unroll
    for (int p = 0; p < 2; ++p) {
      int c = p * 256 + tid;
      gload_lds16(tile + (size_t)c * 8, dst + (p * 256 + w * 64) * 8);
    }
  };
  auto compute = [&](const __bf16* Ab, const __bf16* Bb) {
    bf16x8 af[2][2], bfr[4][2];
#pragma unroll
    for (int i = 0; i < 2; ++i) {
      int m = w * 32 + i * 16 + l15;
#pragma unroll
      for (int kk = 0; kk < 2; ++kk)
        af[i][kk] = *(const bf16x8*)((const char*)Ab + m * 128 + (((kk * 4 + g4) ^ (m & 7)) << 4));
    }
#pragma unroll
    for (int j = 0; j < 4; ++j) {
      int n = j * 16 + l15;
#pragma unroll
      for (int kk = 0; kk < 2; ++kk)
        bfr[j][kk] = *(const bf16x8*)((const char*)Bb + n * 128 + (((kk * 4 + g4) ^ (n & 7)) << 4));
    }
#pragma unroll
    for (int kk = 0; kk < 2; ++kk)
#pragma unroll
      for (int i = 0; i < 2; ++i)
#pragma unroll
        for (int j = 0; j < 4; ++j)
          acc[i][j] = __builtin_amdgcn_mfma_f32_16x16x32_bf16(af[i][kk], bfr[j][kk], acc[i][j], 0, 0, 0);
  };

  issueA(0, As[0]); issueB(0, Bs[0]);
  __syncthreads();

  for (int t = 0; t < NT; t += 2) {
    issueA(t + 1, As[1]); issueB(t + 1, Bs[1]);
    compute(As[0], Bs[0]);
    __syncthreads();
    if (t + 2 < NT) { issueA(t + 2, As[0]); issueB(t + 2, Bs[0]); }
    compute(As[1], Bs[1]);
    __syncthreads();
  }

  if constexpr (MODE == 0) {
#pragma unroll
    for (int i = 0; i < 2; ++i)
#pragma unroll
      for (int j = 0; j < 4; ++j)
#pragma unroll
        for (int r = 0; r < 4; ++r) {
          size_t row = bm * 128 + w * 32 + i * 16 + g4 * 4 + r;
          size_t col = bn * 64 + j * 16 + l15;
          C[row * 4096 + col] = acc[i][j][r];
        }
  } else {
    const int nb0 = bn * 64;
    if (bn < 80) {
      __bf16* dst = (bn < 64) ? Qb : Kb;
      int ldc = (bn < 64) ? 4096 : 1024;
      int coff = (bn < 64) ? 0 : 4096;
#pragma unroll
      for (int i = 0; i < 2; ++i)
#pragma unroll
        for (int j = 0; j < 4; ++j)
#pragma unroll
          for (int r = 0; r < 4; ++r) {
            size_t row = bm * 128 + w * 32 + i * 16 + g4 * 4 + r;
            size_t col = nb0 - coff + j * 16 + l15;
            dst[row * ldc + col] = (__bf16)acc[i][j][r];
          }
    } else {
#pragma unroll
      for (int i = 0; i < 2; ++i)
#pragma unroll
        for (int j = 0; j < 4; ++j) {
          size_t n = nb0 - 5120 + j * 16 + l15;
          size_t m0 = bm * 128 + w * 32 + i * 16 + g4 * 4;
          bf16x4 v;
          v.x = (__bf16)acc[i][j][0]; v.y = (__bf16)acc[i][j][1];
          v.z = (__bf16)acc[i][j][2]; v.w = (__bf16)acc[i][j][3];
          *(bf16x4*)&Vt[n * 1024 + m0] = v;
        }
    }
  }
}

// ---------------- flash attention (round-2 proven) ----------------
__global__ __launch_bounds__(256) void k_attn(const __bf16* __restrict__ Q,
                                              const __bf16* __restrict__ Kb,
                                              const __bf16* __restrict__ Vt,
                                              __bf16* __restrict__ ctx) {
  __shared__ __align__(16) char lds_raw[65536];
  __bf16* Ks = (__bf16*)lds_raw;
  __bf16* Vs = (__bf16*)(lds_raw + 32768);

  const int h = blockIdx.y, g = h >> 2;
  const int q0 = blockIdx.x * 64;
  const int tid = threadIdx.x, w = tid >> 6, l = tid & 63;
  const int l15 = l & 15, g4 = l >> 4;
  const float scale = 0.08838834764831845f;

  bf16x8 qf[4];
  const int qrow = q0 + w * 16 + l15;
#pragma unroll
  for (int ks = 0; ks < 4; ++ks)
    qf[ks] = *(const bf16x8*)&Q[(size_t)qrow * (NH * HD) + h * HD + ks * 32 + g4 * 8];

  f32x4 acc[8];
#pragma unroll
  for (int i = 0; i < 8; ++i)
#pragma unroll
    for (int r = 0; r < 4; ++r) acc[i][r] = 0.f;
  float m_run = -__builtin_inff(), l_run = 0.f;

  const int ntiles = (q0 + 64 + 127) >> 7;
  for (int kt = 0; kt < ntiles; ++kt) {
    const int kv0 = kt * 128;
#pragma unroll
    for (int p = 0; p < 8; ++p) {
      int c = p * 256 + tid;
      int row = c >> 4, cc = c & 15;
      gload_lds16(&Kb[(size_t)(kv0 + row) * (NG * HD) + g * HD + ((cc ^ (row & 7)) << 3)],
                  &Ks[(p * 256 + w * 64) * 8]);
      gload_lds16(&Vt[(size_t)(g * HD + row) * S_LEN + kv0 + ((cc ^ (row & 7)) << 3)],
                  &Vs[(p * 256 + w * 64) * 8]);
    }
    __syncthreads();

    float sreg[8][4];
    const bool need_mask = (kv0 + 127 > q0);
#pragma unroll
    for (int tf = 0; tf < 8; ++tf) {
      f32x4 sa;
#pragma unroll
      for (int r = 0; r < 4; ++r) sa[r] = 0.f;
      int t_loc = tf * 16 + l15;
#pragma unroll
      for (int ks = 0; ks < 4; ++ks) {
        bf16x8 kf = *(const bf16x8*)((const char*)Ks + t_loc * 256 + (((ks * 4 + g4) ^ (t_loc & 7)) << 4));
        sa = __builtin_amdgcn_mfma_f32_16x16x32_bf16(kf, qf[ks], sa, 0, 0, 0);
      }
#pragma unroll
      for (int r = 0; r < 4; ++r) {
        float v = sa[r] * scale;
        if (need_mask && (kv0 + tf * 16 + g4 * 4 + r) > qrow) v = -__builtin_inff();
        sreg[tf][r] = v;
      }
    }
    float mx = -__builtin_inff();
#pragma unroll
    for (int tf = 0; tf < 8; ++tf)
#pragma unroll
      for (int r = 0; r < 4; ++r) mx = fmaxf(mx, sreg[tf][r]);
    mx = fmaxf(mx, __shfl_xor(mx, 16));
    mx = fmaxf(mx, __shfl_xor(mx, 32));
    const float m_new = fmaxf(m_run, mx);
    const float alpha = __expf(m_run - m_new);
    float ssum = 0.f;
#pragma unroll
    for (int tf = 0; tf < 8; ++tf)
#pragma unroll
      for (int r = 0; r < 4; ++r) {
        sreg[tf][r] = __expf(sreg[tf][r] - m_new);
        ssum += sreg[tf][r];
      }
    ssum += __shfl_xor(ssum, 16);
    ssum += __shfl_xor(ssum, 32);
    l_run = l_run * alpha + ssum;
    m_run = m_new;
    float ar[4];
#pragma unroll
    for (int r = 0; r < 4; ++r) ar[r] = __shfl(alpha, g4 * 4 + r);
#pragma unroll
    for (int nf = 0; nf < 8; ++nf)
#pragma unroll
      for (int r = 0; r < 4; ++r) acc[nf][r] *= ar[r];

    __syncthreads();

    char* pb = lds_raw + w * 4096;
#pragma unroll
    for (int tf = 0; tf < 8; ++tf) {
      int chunkc = 2 * tf + (g4 >> 1);
      int addr = l15 * 256 + ((chunkc ^ (l15 & 7)) << 4) + ((g4 & 1) << 3);
      *(unsigned*)(pb + addr)     = pack2bf(sreg[tf][0], sreg[tf][1]);
      *(unsigned*)(pb + addr + 4) = pack2bf(sreg[tf][2], sreg[tf][3]);
    }
    asm volatile("s_waitcnt lgkmcnt(0)" ::: "memory");
    bf16x8 pf[4];
#pragma unroll
    for (int ks = 0; ks < 4; ++ks)
      pf[ks] = *(const bf16x8*)(pb + l15 * 256 + (((ks * 4 + g4) ^ (l15 & 7)) << 4));
#pragma unroll
    for (int nf = 0; nf < 8; ++nf) {
      int d_loc = nf * 16 + l15;
#pragma unroll
      for (int ks = 0; ks < 4; ++ks) {
        bf16x8 vf = *(const bf16x8*)((const char*)Vs + d_loc * 256 + (((ks * 4 + g4) ^ (d_loc & 7)) << 4));
        acc[nf] = __builtin_amdgcn_mfma_f32_16x16x32_bf16(pf[ks], vf, acc[nf], 0, 0, 0);
      }
    }
    __syncthreads();
  }
  float li[4];
#pragma unroll
  for (int r = 0; r < 4; ++r) li[r] = 1.f / __shfl(l_run, g4 * 4 + r);
#pragma unroll
  for (int nf = 0; nf < 8; ++nf)
#pragma unroll
    for (int r = 0; r < 4; ++r) {
      size_t row = q0 + w * 16 + g4 * 4 + r;
      size_t col = (size_t)h * HD + nf * 16 + l15;
      ctx[row * (NH * HD) + col] = (__bf16)(acc[nf][r] * li[r]);
    }
}

// ---------------- host ----------------
extern "C" void kernel_launch(void* const* d_in, const int* in_sizes, int n_in,
                              void* d_out, int out_size, void* d_ws, size_t ws_size,
                              hipStream_t stream) {
  const float* x    = (const float*)d_in[0];
  const float* cosT = (const float*)d_in[2];
  const float* sinT = (const float*)d_in[3];
  const float* Wq   = (const float*)d_in[4];
  const float* Wk   = (const float*)d_in[5];
  const float* Wv   = (const float*)d_in[6];
  const float* Wo   = (const float*)d_in[7];
  float* out = (float*)d_out;

  char* ws = (char*)d_ws;
  const size_t MB = 1u << 20;
  __bf16* xb    = (__bf16*)(ws + 0);        // 8 MB : x bf16; reused as ctx after QKV
  __bf16* WqkvT = (__bf16*)(ws + 8 * MB);   // 48 MB: tiled [96 tn][64 tk] 8KB tiles
  __bf16* WoT   = (__bf16*)(ws + 56 * MB);  // 32 MB: tiled [64 tn][64 tk] 8KB tiles
  __bf16* Qb    = (__bf16*)(ws + 88 * MB);  // 8 MB : Q, roped in-place
  __bf16* Kbuf  = (__bf16*)(ws + 96 * MB);  // 2 MB : K, roped in-place
  __bf16* Vtb   = (__bf16*)(ws + 98 * MB);  // 2 MB : V^T (direct from epilogue)
  __bf16* ctxb  = (__bf16*)(ws + 0);        // aliases xb

  // 4096 cast blocks + 40 n-strips x 64 k-tiles = 2560 transpose blocks
  k_prep<<<4096 + 2560, 256, 0, stream>>>(x, Wq, Wk, Wv, Wo, xb, WqkvT, WoT);

  // fused QKV: (1024 x 6144), V written transposed
  k_gemm<1><<<dim3(96, 8), 256, 0, stream>>>(xb, WqkvT, nullptr, Qb, Kbuf, Vtb);

  k_rope<<<2560, 256, 0, stream>>>(Qb, Kbuf, cosT, sinT);

  k_attn<<<dim3(16, 32), 256, 0, stream>>>(Qb, Kbuf, Vtb, ctxb);

  // out = ctx * WoT^T (1024 x 4096), f32
  k_gemm<0><<<dim3(64, 8), 256, 0, stream>>>(ctxb, WoT, out, nullptr, nullptr, nullptr);
}

// Round 10
// 200.964 us; speedup vs baseline: 1.0891x; 1.0555x over previous
//
#include <hip/hip_runtime.h>
#include <hip/hip_bf16.h>

#define S_LEN 1024
#define DIN 4096
#define NH 32
#define NG 8
#define HD 128

typedef __bf16 bf16x8 __attribute__((ext_vector_type(8)));
typedef __bf16 bf16x4 __attribute__((ext_vector_type(4)));
typedef float f32x4 __attribute__((ext_vector_type(4)));

__device__ __forceinline__ void gload_lds16(const void* g, void* l) {
  __builtin_amdgcn_global_load_lds(
      (const __attribute__((address_space(1))) unsigned int*)g,
      (__attribute__((address_space(3))) unsigned int*)l, 16, 0, 0);
}

__device__ __forceinline__ unsigned pack2bf(float a, float b) {
  union { __bf16 h[2]; unsigned u; } x;
  x.h[0] = (__bf16)a; x.h[1] = (__bf16)b;
  return x.u;
}

// ---------------- cast x: f32 -> bf16 (the only remaining prep) ----------------
__global__ __launch_bounds__(256) void k_cast(const float* __restrict__ in,
                                              __bf16* __restrict__ out, int n4) {
  int i = blockIdx.x * 256 + threadIdx.x;
  if (i >= n4) return;
  const float4 v = ((const float4*)in)[i];
  bf16x4 o;
  o.x = (__bf16)v.x; o.y = (__bf16)v.y; o.z = (__bf16)v.z; o.w = (__bf16)v.w;
  ((bf16x4*)out)[i] = o;
}

// ---------------- RoPE, vectorized: 4 d-pairs per thread ----------------
__global__ __launch_bounds__(256) void k_rope(__bf16* __restrict__ Q, __bf16* __restrict__ Kb,
                                              const float* __restrict__ cosT,
                                              const float* __restrict__ sinT) {
  int idx = blockIdx.x * 256 + threadIdx.x;
  int d = (idx & 15) * 4;
  int row = idx >> 4;
  __bf16* p; int s;
  if (row < S_LEN * NH) { p = Q + (size_t)row * HD; s = row >> 5; }
  else { int r = row - S_LEN * NH; p = Kb + (size_t)r * HD; s = r >> 3; }
  const float4 c = *(const float4*)&cosT[s * HD + d];
  const float4 sn = *(const float4*)&sinT[s * HD + d];
  bf16x4 a = *(const bf16x4*)&p[d];
  bf16x4 b = *(const bf16x4*)&p[d + 64];
  bf16x4 oa, ob;
  oa.x = (__bf16)((float)a.x * c.x - (float)b.x * sn.x);
  oa.y = (__bf16)((float)a.y * c.y - (float)b.y * sn.y);
  oa.z = (__bf16)((float)a.z * c.z - (float)b.z * sn.z);
  oa.w = (__bf16)((float)a.w * c.w - (float)b.w * sn.w);
  ob.x = (__bf16)((float)b.x * c.x + (float)a.x * sn.x);
  ob.y = (__bf16)((float)b.y * c.y + (float)a.y * sn.y);
  ob.z = (__bf16)((float)b.z * c.z + (float)a.z * sn.z);
  ob.w = (__bf16)((float)b.w * c.w + (float)a.w * sn.w);
  *(bf16x4*)&p[d] = oa;
  *(bf16x4*)&p[d + 64] = ob;
}

// ---------------- GEMM: C(M,N) = A(M,K,bf16) * W(K,N,f32) ----------------
// BM=128, BN=64, BK=64. 4 waves. No transposed-weight materialization (r9
// post-mortem: the 88MB d_ws write stream is a ~1.1TB/s floor; 5 transpose
// variants all ~80us). W consumed in natural (K,N) f32 layout:
//   per K-tile, reg-stage 2 row-pair float4 loads/thread (256B-coalesced,
//   L3-resident after first touch), pack k-pairs to bf16 dwords (cvt_pk),
//   store to LDS dword tile Bp[32 kp][16 chunk][4] at cphys=(nn>>2)^(kp&7).
// Bank audit (fixes r3's 4-way frag-read conflict, SQ_LDS_BANK_CONFLICT 12.58M):
//   writeB b128: per wave 256 dwords uniform 8/bank = the 1024B floor, 0 conflict.
//   frag ds_read_b32: banks ((((n>>2)^(kp&7))&7)<<2)|(n&3) -> 32 banks x 2-way (free).
// A path unchanged (DMA + XOR chunk swizzle, proven 0-conflict). Double-buffered.
// MODE 0: f32 C (N=4096). MODE 1: QKV split epilogue (Q,K bf16; V transposed).
template <int MODE>
__global__ __launch_bounds__(256, 3) void k_gemm(const __bf16* __restrict__ A,
                                                 const float* __restrict__ W0,
                                                 const float* __restrict__ W1,
                                                 const float* __restrict__ W2,
                                                 float* __restrict__ C,
                                                 __bf16* __restrict__ Qb,
                                                 __bf16* __restrict__ Kb,
                                                 __bf16* __restrict__ Vt) {
  __shared__ __bf16 As[2][128 * 64];
  __shared__ unsigned Bp[2][32 * 64];   // 2 x 8KB dword tiles
  const int bm = blockIdx.y, bn = blockIdx.x;
  const int K = DIN, NT = K / 64;

  const float* Wsrc; int ldb, nloc;
  if (MODE == 0) { Wsrc = W0; ldb = 4096; nloc = bn * 64; }
  else {
    if (bn < 64)      { Wsrc = W0; ldb = 4096; nloc = bn * 64; }
    else if (bn < 80) { Wsrc = W1; ldb = 1024; nloc = (bn - 64) * 64; }
    else              { Wsrc = W2; ldb = 1024; nloc = (bn - 80) * 64; }
  }

  const int tid = threadIdx.x, w = tid >> 6;
  const int l = tid & 63, l15 = l & 15, g4 = l >> 4;

  const __bf16* Asrc = A + (size_t)(bm * 128) * K;

  f32x4 acc[2][4];
#pragma unroll
  for (int i = 0; i < 2; ++i)
#pragma unroll
    for (int j = 0; j < 4; ++j)
#pragma unroll
      for (int r = 0; r < 4; ++r) acc[i][j][r] = 0.f;

  // per-thread B staging regs: 2 slots x 2 rows
  float4 breg[2][2];
  const int kp_s[2] = {tid >> 4, 16 + (tid >> 4)};      // slot kp
  const int nn_s = (tid & 15) * 4;                      // slot col group

  auto loadB = [&](int t) {
#pragma unroll
    for (int p = 0; p < 2; ++p) {
      const float* src = Wsrc + (size_t)(t * 64 + 2 * kp_s[p]) * ldb + nloc + nn_s;
      breg[p][0] = *(const float4*)src;
      breg[p][1] = *(const float4*)(src + ldb);
    }
  };
  auto writeB = [&](unsigned* dst) {
#pragma unroll
    for (int p = 0; p < 2; ++p) {
      int kp = kp_s[p];
      int cphys = (nn_s >> 2) ^ (kp & 7);
      uint4 d;
      d.x = pack2bf(breg[p][0].x, breg[p][1].x);
      d.y = pack2bf(breg[p][0].y, breg[p][1].y);
      d.z = pack2bf(breg[p][0].z, breg[p][1].z);
      d.w = pack2bf(breg[p][0].w, breg[p][1].w);
      *(uint4*)&dst[kp * 64 + cphys * 4] = d;
    }
  };
  auto issueA = [&](int t, __bf16* dst) {
#pragma unroll
    for (int p = 0; p < 4; ++p) {
      int c = p * 256 + tid;
      int row = c >> 3, gc = (c & 7) ^ (row & 7);
      gload_lds16(Asrc + (size_t)row * K + t * 64 + gc * 8, dst + (p * 256 + w * 64) * 8);
    }
  };
  auto compute = [&](const __bf16* Ab, const unsigned* Bp_) {
    bf16x8 af[2][2];
#pragma unroll
    for (int i = 0; i < 2; ++i) {
      int m = w * 32 + i * 16 + l15;
#pragma unroll
      for (int kk = 0; kk < 2; ++kk)
        af[i][kk] = *(const bf16x8*)((const char*)Ab + m * 128 + (((kk * 4 + g4) ^ (m & 7)) << 4));
    }
    unsigned fbu[2][4][4];
#pragma unroll
    for (int kk = 0; kk < 2; ++kk)
#pragma unroll
      for (int j = 0; j < 4; ++j) {
        int n = j * 16 + l15;
#pragma unroll
        for (int d = 0; d < 4; ++d) {
          int kp = kk * 16 + g4 * 4 + d;
          fbu[kk][j][d] = Bp_[kp * 64 + (((n >> 2) ^ (kp & 7)) << 2) + (n & 3)];
        }
      }
#pragma unroll
    for (int kk = 0; kk < 2; ++kk)
#pragma unroll
      for (int j = 0; j < 4; ++j) {
        union { unsigned u[4]; bf16x8 v; } fb;
        fb.u[0] = fbu[kk][j][0]; fb.u[1] = fbu[kk][j][1];
        fb.u[2] = fbu[kk][j][2]; fb.u[3] = fbu[kk][j][3];
#pragma unroll
        for (int i = 0; i < 2; ++i)
          acc[i][j] = __builtin_amdgcn_mfma_f32_16x16x32_bf16(af[i][kk], fb.v, acc[i][j], 0, 0, 0);
      }
  };

  // prologue: tile 0 into buffer 0
  loadB(0);
  issueA(0, As[0]);
  writeB(Bp[0]);      // waits vmcnt for breg deps
  __syncthreads();    // drains A DMA + ds_writes

  for (int t = 0; t < NT; t += 2) {
    // buf0 holds t: prefetch t+1 (B->regs, A->DMA buf1), compute t
    loadB(t + 1);
    issueA(t + 1, As[1]);
    compute(As[0], Bp[0]);
    writeB(Bp[1]);    // write other buffer (no reader yet)
    __syncthreads();  // buf1 ready
    if (t + 2 < NT) {
      loadB(t + 2);
      issueA(t + 2, As[0]);
    }
    compute(As[1], Bp[1]);
    if (t + 2 < NT) writeB(Bp[0]);
    __syncthreads();
  }

  // ---- epilogue ----
  if constexpr (MODE == 0) {
#pragma unroll
    for (int i = 0; i < 2; ++i)
#pragma unroll
      for (int j = 0; j < 4; ++j)
#pragma unroll
        for (int r = 0; r < 4; ++r) {
          size_t row = bm * 128 + w * 32 + i * 16 + g4 * 4 + r;
          size_t col = bn * 64 + j * 16 + l15;
          C[row * 4096 + col] = acc[i][j][r];
        }
  } else {
    if (bn < 80) {
      __bf16* dst = (bn < 64) ? Qb : Kb;
      int ldc = (bn < 64) ? 4096 : 1024;
#pragma unroll
      for (int i = 0; i < 2; ++i)
#pragma unroll
        for (int j = 0; j < 4; ++j)
#pragma unroll
          for (int r = 0; r < 4; ++r) {
            size_t row = bm * 128 + w * 32 + i * 16 + g4 * 4 + r;
            size_t col = (size_t)nloc + j * 16 + l15;
            dst[row * ldc + col] = (__bf16)acc[i][j][r];
          }
    } else {
      // V: write transposed -> Vt[n][s]
#pragma unroll
      for (int i = 0; i < 2; ++i)
#pragma unroll
        for (int j = 0; j < 4; ++j) {
          size_t n = (size_t)nloc + j * 16 + l15;
          size_t m0 = bm * 128 + w * 32 + i * 16 + g4 * 4;
          bf16x4 v;
          v.x = (__bf16)acc[i][j][0]; v.y = (__bf16)acc[i][j][1];
          v.z = (__bf16)acc[i][j][2]; v.w = (__bf16)acc[i][j][3];
          *(bf16x4*)&Vt[n * 1024 + m0] = v;
        }
    }
  }
}

// ---------------- flash attention (round-2 proven) ----------------
__global__ __launch_bounds__(256) void k_attn(const __bf16* __restrict__ Q,
                                              const __bf16* __restrict__ Kb,
                                              const __bf16* __restrict__ Vt,
                                              __bf16* __restrict__ ctx) {
  __shared__ __align__(16) char lds_raw[65536];
  __bf16* Ks = (__bf16*)lds_raw;
  __bf16* Vs = (__bf16*)(lds_raw + 32768);

  const int h = blockIdx.y, g = h >> 2;
  const int q0 = blockIdx.x * 64;
  const int tid = threadIdx.x, w = tid >> 6, l = tid & 63;
  const int l15 = l & 15, g4 = l >> 4;
  const float scale = 0.08838834764831845f;

  bf16x8 qf[4];
  const int qrow = q0 + w * 16 + l15;
#pragma unroll
  for (int ks = 0; ks < 4; ++ks)
    qf[ks] = *(const bf16x8*)&Q[(size_t)qrow * (NH * HD) + h * HD + ks * 32 + g4 * 8];

  f32x4 acc[8];
#pragma unroll
  for (int i = 0; i < 8; ++i)
#pragma unroll
    for (int r = 0; r < 4; ++r) acc[i][r] = 0.f;
  float m_run = -__builtin_inff(), l_run = 0.f;

  const int ntiles = (q0 + 64 + 127) >> 7;
  for (int kt = 0; kt < ntiles; ++kt) {
    const int kv0 = kt * 128;
#pragma unroll
    for (int p = 0; p < 8; ++p) {
      int c = p * 256 + tid;
      int row = c >> 4, cc = c & 15;
      gload_lds16(&Kb[(size_t)(kv0 + row) * (NG * HD) + g * HD + ((cc ^ (row & 7)) << 3)],
                  &Ks[(p * 256 + w * 64) * 8]);
      gload_lds16(&Vt[(size_t)(g * HD + row) * S_LEN + kv0 + ((cc ^ (row & 7)) << 3)],
                  &Vs[(p * 256 + w * 64) * 8]);
    }
    __syncthreads();

    float sreg[8][4];
    const bool need_mask = (kv0 + 127 > q0);
#pragma unroll
    for (int tf = 0; tf < 8; ++tf) {
      f32x4 sa;
#pragma unroll
      for (int r = 0; r < 4; ++r) sa[r] = 0.f;
      int t_loc = tf * 16 + l15;
#pragma unroll
      for (int ks = 0; ks < 4; ++ks) {
        bf16x8 kf = *(const bf16x8*)((const char*)Ks + t_loc * 256 + (((ks * 4 + g4) ^ (t_loc & 7)) << 4));
        sa = __builtin_amdgcn_mfma_f32_16x16x32_bf16(kf, qf[ks], sa, 0, 0, 0);
      }
#pragma unroll
      for (int r = 0; r < 4; ++r) {
        float v = sa[r] * scale;
        if (need_mask && (kv0 + tf * 16 + g4 * 4 + r) > qrow) v = -__builtin_inff();
        sreg[tf][r] = v;
      }
    }
    float mx = -__builtin_inff();
#pragma unroll
    for (int tf = 0; tf < 8; ++tf)
#pragma unroll
      for (int r = 0; r < 4; ++r) mx = fmaxf(mx, sreg[tf][r]);
    mx = fmaxf(mx, __shfl_xor(mx, 16));
    mx = fmaxf(mx, __shfl_xor(mx, 32));
    const float m_new = fmaxf(m_run, mx);
    const float alpha = __expf(m_run - m_new);
    float ssum = 0.f;
#pragma unroll
    for (int tf = 0; tf < 8; ++tf)
#pragma unroll
      for (int r = 0; r < 4; ++r) {
        sreg[tf][r] = __expf(sreg[tf][r] - m_new);
        ssum += sreg[tf][r];
      }
    ssum += __shfl_xor(ssum, 16);
    ssum += __shfl_xor(ssum, 32);
    l_run = l_run * alpha + ssum;
    m_run = m_new;
    float ar[4];
#pragma unroll
    for (int r = 0; r < 4; ++r) ar[r] = __shfl(alpha, g4 * 4 + r);
#pragma unroll
    for (int nf = 0; nf < 8; ++nf)
#pragma unroll
      for (int r = 0; r < 4; ++r) acc[nf][r] *= ar[r];

    __syncthreads();

    char* pb = lds_raw + w * 4096;
#pragma unroll
    for (int tf = 0; tf < 8; ++tf) {
      int chunkc = 2 * tf + (g4 >> 1);
      int addr = l15 * 256 + ((chunkc ^ (l15 & 7)) << 4) + ((g4 & 1) << 3);
      *(unsigned*)(pb + addr)     = pack2bf(sreg[tf][0], sreg[tf][1]);
      *(unsigned*)(pb + addr + 4) = pack2bf(sreg[tf][2], sreg[tf][3]);
    }
    asm volatile("s_waitcnt lgkmcnt(0)" ::: "memory");
    bf16x8 pf[4];
#pragma unroll
    for (int ks = 0; ks < 4; ++ks)
      pf[ks] = *(const bf16x8*)(pb + l15 * 256 + (((ks * 4 + g4) ^ (l15 & 7)) << 4));
#pragma unroll
    for (int nf = 0; nf < 8; ++nf) {
      int d_loc = nf * 16 + l15;
#pragma unroll
      for (int ks = 0; ks < 4; ++ks) {
        bf16x8 vf = *(const bf16x8*)((const char*)Vs + d_loc * 256 + (((ks * 4 + g4) ^ (d_loc & 7)) << 4));
        acc[nf] = __builtin_amdgcn_mfma_f32_16x16x32_bf16(pf[ks], vf, acc[nf], 0, 0, 0);
      }
    }
    __syncthreads();
  }
  float li[4];
#pragma unroll
  for (int r = 0; r < 4; ++r) li[r] = 1.f / __shfl(l_run, g4 * 4 + r);
#pragma unroll
  for (int nf = 0; nf < 8; ++nf)
#pragma unroll
    for (int r = 0; r < 4; ++r) {
      size_t row = q0 + w * 16 + g4 * 4 + r;
      size_t col = (size_t)h * HD + nf * 16 + l15;
      ctx[row * (NH * HD) + col] = (__bf16)(acc[nf][r] * li[r]);
    }
}

// ---------------- host ----------------
extern "C" void kernel_launch(void* const* d_in, const int* in_sizes, int n_in,
                              void* d_out, int out_size, void* d_ws, size_t ws_size,
                              hipStream_t stream) {
  const float* x    = (const float*)d_in[0];
  const float* cosT = (const float*)d_in[2];
  const float* sinT = (const float*)d_in[3];
  const float* Wq   = (const float*)d_in[4];
  const float* Wk   = (const float*)d_in[5];
  const float* Wv   = (const float*)d_in[6];
  const float* Wo   = (const float*)d_in[7];
  float* out = (float*)d_out;

  char* ws = (char*)d_ws;
  const size_t MB = 1u << 20;
  __bf16* xb   = (__bf16*)(ws + 0);        // 8 MB : x bf16; reused as ctx after QKV
  __bf16* Qb   = (__bf16*)(ws + 8 * MB);   // 8 MB : Q, roped in-place
  __bf16* Kbuf = (__bf16*)(ws + 16 * MB);  // 2 MB : K, roped in-place
  __bf16* Vtb  = (__bf16*)(ws + 18 * MB);  // 2 MB : V^T (direct from epilogue)
  __bf16* ctxb = (__bf16*)(ws + 0);        // aliases xb (dead after QKV GEMM)

  k_cast<<<4096, 256, 0, stream>>>(x, xb, (S_LEN * DIN) / 4);

  // fused QKV: consumes f32 weights directly (no transposed copies in HBM)
  k_gemm<1><<<dim3(96, 8), 256, 0, stream>>>(xb, Wq, Wk, Wv, nullptr, Qb, Kbuf, Vtb);

  k_rope<<<2560, 256, 0, stream>>>(Qb, Kbuf, cosT, sinT);

  k_attn<<<dim3(16, 32), 256, 0, stream>>>(Qb, Kbuf, Vtb, ctxb);

  // out = ctx * Wo (f32 weights direct), f32 out
  k_gemm<0><<<dim3(64, 8), 256, 0, stream>>>(ctxb, Wo, nullptr, nullptr, out,
                                             nullptr, nullptr, nullptr);
}